// Round 1
// baseline (643.998 us; speedup 1.0000x reference)
//
#include <hip/hip_runtime.h>

typedef unsigned long long u64;
typedef unsigned int u32;

#define NA 10000
#define NE 320000
#define KN 10
#define NSPLIT 4
#define KCHUNK (NA / NSPLIT)   // 2500

// ---------------- top-10 (d2,idx) maintenance ----------------
__device__ __forceinline__ void insert10(u64* top, u64 key) {
#pragma unroll
  for (int t = 9; t > 0; --t) {
    u64 prev = top[t - 1];
    u64 cur = top[t];
    top[t] = (key < prev) ? prev : ((key < cur) ? key : cur);
  }
  top[0] = (key < top[0]) ? key : top[0];
}

// ---------------- neighbor search: partial top-10 per (graph, query, split) ----------------
__global__ __launch_bounds__(256) void k_nbr(const float2* __restrict__ apos,
                                             const float2* __restrict__ tpos,
                                             u64* __restrict__ part) {
  const int bid = blockIdx.x;
  const int graph = bid / (NSPLIT * 40);
  const int rem = bid % (NSPLIT * 40);
  const int split = rem / 40;
  const int qb = (rem % 40) * 256;
  const int q = qb + threadIdx.x;
  const float2* kpos = graph ? tpos : apos;
  const int kb = split * KCHUNK;

  __shared__ float2 kt[KCHUNK];
  for (int i = threadIdx.x; i < KCHUNK; i += 256) kt[i] = kpos[kb + i];
  __syncthreads();

  if (q >= NA) return;

  u64 top[10];
#pragma unroll
  for (int t = 0; t < 10; ++t) top[t] = ~0ull;

  float2 qp = apos[q];
  for (int j = 0; j < KCHUNK; ++j) {
    float2 kp = kt[j];
    float dx = qp.x - kp.x;
    float dy = qp.y - kp.y;
    float d2 = __fadd_rn(__fmul_rn(dx, dx), __fmul_rn(dy, dy));
    int g = kb + j;
    if (d2 <= 4.0f && !(graph == 0 && g == q)) {
      u64 key = ((u64)__float_as_uint(d2) << 32) | (u32)g;
      if (key < top[9]) insert10(top, key);
    }
  }
  u64* o = part + ((size_t)(graph * NA + q) * NSPLIT + split) * 10;
#pragma unroll
  for (int t = 0; t < 10; ++t) o[t] = top[t];
}

__global__ __launch_bounds__(256) void k_merge(const u64* __restrict__ part,
                                               int* __restrict__ a_idx, int* __restrict__ a_cnt,
                                               int* __restrict__ t_idx, int* __restrict__ t_cnt) {
  int tid = blockIdx.x * 256 + threadIdx.x;
  if (tid >= 2 * NA) return;
  int graph = tid / NA;
  int q = tid - graph * NA;
  const u64* p = part + (size_t)(graph * NA + q) * (NSPLIT * 10);
  u64 top[10];
#pragma unroll
  for (int t = 0; t < 10; ++t) top[t] = ~0ull;
  for (int i = 0; i < NSPLIT * 10; ++i) {
    u64 key = p[i];
    if (key < top[9]) insert10(top, key);
  }
  int cnt = 0;
#pragma unroll
  for (int t = 0; t < 10; ++t) cnt += (top[t] != ~0ull) ? 1 : 0;
  int* oi = graph ? t_idx : a_idx;
#pragma unroll
  for (int t = 0; t < 10; ++t) oi[(size_t)q * 10 + t] = (int)(u32)(top[t] & 0xffffffffu);
  if (graph) t_cnt[q] = cnt; else a_cnt[q] = cnt;
}

// ---------------- GATv2 (32 channels, K<=10), fully unrolled ----------------
__device__ __forceinline__ void gat32(float qx, float qy,
                                      const float2* __restrict__ srcpos,
                                      const int* __restrict__ idxlist, int cnt,
                                      const float* __restrict__ Wl, const float* __restrict__ Wr,
                                      const float* __restrict__ att, const float* __restrict__ bb,
                                      float* __restrict__ out) {
  float xr[32];
#pragma unroll
  for (int c = 0; c < 32; ++c) xr[c] = qx * Wr[c] + qy * Wr[32 + c];
  float pjx[10], pjy[10], pv[10];
  float m = -1e30f;
#pragma unroll
  for (int k = 0; k < 10; ++k) {
    bool valid = (k < cnt);
    int j = valid ? idxlist[k] : 0;
    float2 p = srcpos[j];
    pjx[k] = p.x; pjy[k] = p.y;
    float sacc = 0.f;
#pragma unroll
    for (int c = 0; c < 32; ++c) {
      float xl = p.x * Wl[c] + p.y * Wl[32 + c];
      float g = xl + xr[c];
      g = (g >= 0.f) ? g : 0.2f * g;
      sacc += att[c] * g;
    }
    pv[k] = sacc;
    m = valid ? fmaxf(m, sacc) : m;
  }
  float sum = 0.f;
#pragma unroll
  for (int k = 0; k < 10; ++k) {
    float e = (k < cnt) ? expf(pv[k] - m) : 0.f;
    pv[k] = e;
    sum += e;
  }
  float inv = 1.f / (sum + 1e-16f);
#pragma unroll
  for (int c = 0; c < 32; ++c) out[c] = bb[c];
#pragma unroll
  for (int k = 0; k < 10; ++k) {
    float a = pv[k] * inv;
#pragma unroll
    for (int c = 0; c < 32; ++c) {
      float xl = pjx[k] * Wl[c] + pjy[k] * Wl[32 + c];
      out[c] += a * xl;
    }
  }
}

__global__ __launch_bounds__(256) void k_buildx(
    const float* __restrict__ own_obs, const float2* __restrict__ apos, const float2* __restrict__ tpos,
    const float* __restrict__ W_self, const float* __restrict__ b_self,
    const float* __restrict__ agWl, const float* __restrict__ agWr,
    const float* __restrict__ agatt, const float* __restrict__ agb,
    const float* __restrict__ tgWl, const float* __restrict__ tgWr,
    const float* __restrict__ tgatt, const float* __restrict__ tgb,
    const int* __restrict__ a_idx, const int* __restrict__ a_cnt,
    const int* __restrict__ t_idx, const int* __restrict__ t_cnt,
    float* __restrict__ x) {
  __shared__ float sW[512], sb[64];
  __shared__ float sagWl[64], sagWr[64], sagatt[32], sagb[32];
  __shared__ float stgWl[64], stgWr[64], stgatt[32], stgb[32];
  int t = threadIdx.x;
  for (int i = t; i < 512; i += 256) sW[i] = W_self[i];
  if (t < 64) { sb[t] = b_self[t]; sagWl[t] = agWl[t]; sagWr[t] = agWr[t]; stgWl[t] = tgWl[t]; stgWr[t] = tgWr[t]; }
  if (t < 32) { sagatt[t] = agatt[t]; sagb[t] = agb[t]; stgatt[t] = tgatt[t]; stgb[t] = tgb[t]; }
  __syncthreads();
  int q = blockIdx.x * 256 + t;
  if (q >= NA) return;

  const float4* op = (const float4*)(own_obs + (size_t)q * 8);
  float4 o0 = op[0], o1 = op[1];
  float obs[8] = {o0.x, o0.y, o0.z, o0.w, o1.x, o1.y, o1.z, o1.w};
  float* xrow = x + (size_t)q * 128;
#pragma unroll
  for (int c4 = 0; c4 < 16; ++c4) {
    float4 v;
    float* vp = (float*)&v;
#pragma unroll
    for (int jj = 0; jj < 4; ++jj) {
      int c = c4 * 4 + jj;
      float s = sb[c];
#pragma unroll
      for (int i = 0; i < 8; ++i) s += obs[i] * sW[i * 64 + c];
      vp[jj] = s;
    }
    *(float4*)(xrow + c4 * 4) = v;
  }

  float2 qp = apos[q];
  float outA[32];
  gat32(qp.x, qp.y, apos, a_idx + (size_t)q * 10, a_cnt[q], sagWl, sagWr, sagatt, sagb, outA);
#pragma unroll
  for (int c4 = 0; c4 < 8; ++c4)
    *(float4*)(xrow + 64 + c4 * 4) = make_float4(outA[c4 * 4], outA[c4 * 4 + 1], outA[c4 * 4 + 2], outA[c4 * 4 + 3]);

  float outT[32];
  gat32(qp.x, qp.y, tpos, t_idx + (size_t)q * 10, t_cnt[q], stgWl, stgWr, stgatt, stgb, outT);
#pragma unroll
  for (int c4 = 0; c4 < 8; ++c4)
    *(float4*)(xrow + 96 + c4 * 4) = make_float4(outT[c4 * 4], outT[c4 * 4 + 1], outT[c4 * 4 + 2], outT[c4 * 4 + 3]);
}

// ---------------- CSR build ----------------
__global__ __launch_bounds__(256) void k_hist(const int* __restrict__ edst, int* __restrict__ deg) {
  int e = blockIdx.x * 256 + threadIdx.x;
  if (e < NE) atomicAdd(&deg[edst[e]], 1);
}

__global__ __launch_bounds__(1024) void k_scan(const int* __restrict__ deg, int* __restrict__ rp) {
  __shared__ int part[1024];
  int t = threadIdx.x;
  int beg = t * 10, end = beg + 10;
  if (end > NA) end = NA;
  if (beg > NA) beg = NA;
  int s = 0;
  for (int i = beg; i < end; ++i) s += deg[i];
  part[t] = s;
  __syncthreads();
  for (int o = 1; o < 1024; o <<= 1) {
    int v = part[t];
    int u = (t >= o) ? part[t - o] : 0;
    __syncthreads();
    part[t] = v + u;
    __syncthreads();
  }
  int base = (t > 0) ? part[t - 1] : 0;
  for (int i = beg; i < end; ++i) { rp[i] = base; base += deg[i]; }
  if (t == 1023) rp[NA] = part[1023];
}

__global__ __launch_bounds__(256) void k_scatter(const int* __restrict__ esrc, const int* __restrict__ edst,
                                                 const int* __restrict__ rp, int* __restrict__ cur,
                                                 int* __restrict__ col) {
  int e = blockIdx.x * 256 + threadIdx.x;
  if (e < NE) {
    int d = edst[e];
    int p = atomicAdd(&cur[d], 1);
    col[rp[d] + p] = esrc[e];
  }
}

// ---------------- one adjacency shift: xout[d] = sum_{e:dst=d} xin[src_e] ----------------
__global__ __launch_bounds__(256) void k_shift(const float* __restrict__ xin, float* __restrict__ xout,
                                               const int* __restrict__ rp, const int* __restrict__ col) {
  int w = blockIdx.x * 4 + (threadIdx.x >> 6);
  int lane = threadIdx.x & 63;
  if (w >= NA) return;
  int beg = rp[w], end = rp[w + 1];
  const float2* xin2 = (const float2*)xin;
  float2 acc = make_float2(0.f, 0.f);
  int j = beg;
  for (; j + 1 < end; j += 2) {
    int s0 = col[j], s1 = col[j + 1];
    float2 v0 = xin2[(size_t)s0 * 64 + lane];
    float2 v1 = xin2[(size_t)s1 * 64 + lane];
    acc.x += v0.x; acc.y += v0.y;
    acc.x += v1.x; acc.y += v1.y;
  }
  if (j < end) {
    int s0 = col[j];
    float2 v0 = xin2[(size_t)s0 * 64 + lane];
    acc.x += v0.x; acc.y += v0.y;
  }
  ((float2*)xout)[(size_t)w * 64 + lane] = acc;
}

// ---------------- fused 4-tap GEMM: y = b + sum_t xs_t @ W_t ----------------
__device__ __forceinline__ void gemm_tap(const float* __restrict__ xptr, const float* __restrict__ Wt,
                                         float (*xs)[128], float acc[4][4], int rowbase, int rgrp, int c0) {
  __syncthreads();
  for (int tt = threadIdx.x; tt < 1024; tt += 256) {
    int r = tt >> 5, cq = tt & 31;
    int gr = rowbase + r;
    float4 v = make_float4(0.f, 0.f, 0.f, 0.f);
    if (gr < NA) v = *(const float4*)(xptr + (size_t)gr * 128 + cq * 4);
    *(float4*)(&xs[r][cq * 4]) = v;
  }
  __syncthreads();
#pragma unroll 4
  for (int k = 0; k < 128; ++k) {
    float4 wv = *(const float4*)(Wt + k * 128 + c0);
    float a0 = xs[rgrp * 4 + 0][k];
    float a1 = xs[rgrp * 4 + 1][k];
    float a2 = xs[rgrp * 4 + 2][k];
    float a3 = xs[rgrp * 4 + 3][k];
    acc[0][0] += a0 * wv.x; acc[0][1] += a0 * wv.y; acc[0][2] += a0 * wv.z; acc[0][3] += a0 * wv.w;
    acc[1][0] += a1 * wv.x; acc[1][1] += a1 * wv.y; acc[1][2] += a1 * wv.z; acc[1][3] += a1 * wv.w;
    acc[2][0] += a2 * wv.x; acc[2][1] += a2 * wv.y; acc[2][2] += a2 * wv.z; acc[2][3] += a2 * wv.w;
    acc[3][0] += a3 * wv.x; acc[3][1] += a3 * wv.y; acc[3][2] += a3 * wv.z; acc[3][3] += a3 * wv.w;
  }
}

__global__ __launch_bounds__(256) void k_gemm4(const float* __restrict__ x0, const float* __restrict__ x1,
                                               const float* __restrict__ x2, const float* __restrict__ x3,
                                               const float* __restrict__ W, const float* __restrict__ b,
                                               float* __restrict__ y) {
  __shared__ float xs[32][128];
  const int rgrp = threadIdx.x >> 5;
  const int cgrp = threadIdx.x & 31;
  const int c0 = cgrp * 4;
  const int rowbase = blockIdx.x * 32;
  float acc[4][4];
  float4 bb = *(const float4*)(b + c0);
#pragma unroll
  for (int i = 0; i < 4; ++i) { acc[i][0] = bb.x; acc[i][1] = bb.y; acc[i][2] = bb.z; acc[i][3] = bb.w; }
  gemm_tap(x0, W, xs, acc, rowbase, rgrp, c0);
  gemm_tap(x1, W + 16384, xs, acc, rowbase, rgrp, c0);
  gemm_tap(x2, W + 32768, xs, acc, rowbase, rgrp, c0);
  gemm_tap(x3, W + 49152, xs, acc, rowbase, rgrp, c0);
#pragma unroll
  for (int i = 0; i < 4; ++i) {
    int r = rowbase + rgrp * 4 + i;
    if (r < NA) *(float4*)(y + (size_t)r * 128 + c0) = make_float4(acc[i][0], acc[i][1], acc[i][2], acc[i][3]);
  }
}

// ---------------- BatchNorm ----------------
__global__ __launch_bounds__(256) void k_bnred(const float* __restrict__ y, double* __restrict__ stats) {
  int c = threadIdx.x & 127;
  int slice = blockIdx.x * 2 + (threadIdx.x >> 7);
  double s = 0.0, ss = 0.0;
  for (int r = slice; r < NA; r += 128) {
    double v = (double)y[(size_t)r * 128 + c];
    s += v;
    ss += v * v;
  }
  atomicAdd(&stats[c], s);
  atomicAdd(&stats[128 + c], ss);
}

__global__ void k_bnfin(const double* __restrict__ stats, const float* __restrict__ gamma,
                        const float* __restrict__ beta, float* __restrict__ AB) {
  int c = threadIdx.x;
  double mu = stats[c] / (double)NA;
  double var = stats[128 + c] / (double)NA - mu * mu;
  double rs = 1.0 / sqrt(var + 1e-5);
  float A = (float)rs * gamma[c];
  float B = beta[c] - (float)(mu * rs) * gamma[c];
  AB[c] = A;
  AB[128 + c] = B;
}

__global__ __launch_bounds__(256) void k_bnapply(const float* __restrict__ y, const float* __restrict__ AB,
                                                 float* __restrict__ x) {
  int i = blockIdx.x * 256 + threadIdx.x;
  int c = i & 127;
  float v = y[i] * AB[c] + AB[128 + c];
  v = (v >= 0.f) ? v : 0.01f * v;
  x[i] += v;
}

// ---------------- readout ----------------
__global__ __launch_bounds__(256) void k_read(const float* __restrict__ x, const float* __restrict__ Wr,
                                              const float* __restrict__ br, float* __restrict__ out) {
  int q = blockIdx.x * 256 + threadIdx.x;
  if (q >= NA) return;
  float a0 = br[0], a1 = br[1];
  const float* xr = x + (size_t)q * 128;
#pragma unroll 8
  for (int c = 0; c < 128; ++c) {
    float v = xr[c];
    a0 += v * Wr[c * 2 + 0];
    a1 += v * Wr[c * 2 + 1];
  }
  out[q * 2 + 0] = a0;
  out[q * 2 + 1] = a1;
}

extern "C" void kernel_launch(void* const* d_in, const int* in_sizes, int n_in,
                              void* d_out, int out_size, void* d_ws, size_t ws_size,
                              hipStream_t stream) {
  (void)in_sizes; (void)n_in; (void)out_size; (void)ws_size;
  const float* own_obs = (const float*)d_in[0];
  const float2* apos = (const float2*)d_in[1];
  const float2* tpos = (const float2*)d_in[2];
  const float* W_self = (const float*)d_in[3];
  const float* b_self = (const float*)d_in[4];
  const float* agWl = (const float*)d_in[5];
  const float* agWr = (const float*)d_in[6];
  const float* agatt = (const float*)d_in[7];
  const float* agb = (const float*)d_in[8];
  const float* tgWl = (const float*)d_in[9];
  const float* tgWr = (const float*)d_in[10];
  const float* tgatt = (const float*)d_in[11];
  const float* tgb = (const float*)d_in[12];
  const float* gfW = (const float*)d_in[13];
  const float* gfb = (const float*)d_in[14];
  const float* bng = (const float*)d_in[15];
  const float* bnb = (const float*)d_in[16];
  const float* Wread = (const float*)d_in[17];
  const float* bread = (const float*)d_in[18];
  const int* ei = (const int*)d_in[19];
  const int* esrc = ei;
  const int* edst = ei + NE;

  char* w = (char*)d_ws;
  size_t off = 0;
  auto take = [&](size_t bytes) -> void* {
    void* p = w + off;
    off += (bytes + 255) & ~(size_t)255;
    return p;
  };
  int* a_idx = (int*)take((size_t)NA * KN * 4);
  int* t_idx = (int*)take((size_t)NA * KN * 4);
  int* a_cnt = (int*)take((size_t)NA * 4);
  int* t_cnt = (int*)take((size_t)NA * 4);
  float* x = (float*)take((size_t)NA * 128 * 4);
  float* y = (float*)take((size_t)NA * 128 * 4);
  float* sh1 = (float*)take((size_t)NA * 128 * 4);
  float* sh2 = (float*)take((size_t)NA * 128 * 4);
  float* sh3 = (float*)take((size_t)NA * 128 * 4);
  double* stats = (double*)take(256 * 8 + 256 * 4);  // 256 doubles + 256 floats (A,B)
  float* AB = (float*)(stats + 256);
  int* deg = (int*)take((size_t)NA * 4);
  int* rp = (int*)take((size_t)(NA + 1) * 4);
  int* col = (int*)take((size_t)NE * 4);
  u64* part = (u64*)take((size_t)2 * NA * NSPLIT * 10 * 8);

  // CSR build
  hipMemsetAsync(deg, 0, (size_t)NA * 4, stream);
  k_hist<<<(NE + 255) / 256, 256, 0, stream>>>(edst, deg);
  k_scan<<<1, 1024, 0, stream>>>(deg, rp);
  hipMemsetAsync(deg, 0, (size_t)NA * 4, stream);
  k_scatter<<<(NE + 255) / 256, 256, 0, stream>>>(esrc, edst, rp, deg, col);

  // neighbor search + merge
  k_nbr<<<2 * NSPLIT * 40, 256, 0, stream>>>(apos, tpos, part);
  k_merge<<<(2 * NA + 255) / 256, 256, 0, stream>>>(part, a_idx, a_cnt, t_idx, t_cnt);

  // build x = [self | gat_a | gat_t]
  k_buildx<<<(NA + 255) / 256, 256, 0, stream>>>(own_obs, apos, tpos, W_self, b_self,
                                                 agWl, agWr, agatt, agb, tgWl, tgWr, tgatt, tgb,
                                                 a_idx, a_cnt, t_idx, t_cnt, x);

  // two graph-filter + BN + residual layers
  for (int l = 0; l < 2; ++l) {
    const float* Wl = gfW + (size_t)l * 4 * 128 * 128;
    const float* bl = gfb + (size_t)l * 128;
    const float* gl = bng + (size_t)l * 128;
    const float* bb = bnb + (size_t)l * 128;
    k_shift<<<NA / 4, 256, 0, stream>>>(x, sh1, rp, col);
    k_shift<<<NA / 4, 256, 0, stream>>>(sh1, sh2, rp, col);
    k_shift<<<NA / 4, 256, 0, stream>>>(sh2, sh3, rp, col);
    k_gemm4<<<(NA + 31) / 32, 256, 0, stream>>>(x, sh1, sh2, sh3, Wl, bl, y);
    hipMemsetAsync(stats, 0, 256 * 8, stream);
    k_bnred<<<64, 256, 0, stream>>>(y, stats);
    k_bnfin<<<1, 128, 0, stream>>>(stats, gl, bb, AB);
    k_bnapply<<<(NA * 128) / 256, 256, 0, stream>>>(y, AB, x);
  }

  k_read<<<(NA + 255) / 256, 256, 0, stream>>>(x, Wread, bread, (float*)d_out);
}

// Round 2
// 453.057 us; speedup vs baseline: 1.4214x; 1.4214x over previous
//
#include <hip/hip_runtime.h>

typedef unsigned long long u64;
typedef unsigned int u32;

#define NA 10000
#define NE 320000
#define KN 10
#define GRID 50
#define NCELL (GRID * GRID)      // 2500 cells of width 2.0 over [0,100)^2

// ---------------- top-10 (d2,idx) maintenance ----------------
__device__ __forceinline__ void insert10(u64* top, u64 key) {
#pragma unroll
  for (int t = 9; t > 0; --t) {
    u64 prev = top[t - 1];
    u64 cur = top[t];
    top[t] = (key < prev) ? prev : ((key < cur) ? key : cur);
  }
  top[0] = (key < top[0]) ? key : top[0];
}

__device__ __forceinline__ int cell_of(float2 p) {
  int cx = (int)(p.x * 0.5f);            // exact: *0.5 is a pow2 multiply
  int cy = (int)(p.y * 0.5f);
  cx = min(max(cx, 0), GRID - 1);
  cy = min(max(cy, 0), GRID - 1);
  return cy * GRID + cx;
}

// ---------------- cell binning: hist / scan / scatter ----------------
__global__ __launch_bounds__(256) void k_cellhist(const float2* __restrict__ apos,
                                                  const float2* __restrict__ tpos,
                                                  int* __restrict__ hist) {
  int i = blockIdx.x * 256 + threadIdx.x;
  if (i >= 2 * NA) return;
  int graph = (i >= NA) ? 1 : 0;
  int idx = i - graph * NA;
  float2 p = graph ? tpos[idx] : apos[idx];
  atomicAdd(&hist[graph * NCELL + cell_of(p)], 1);
}

__global__ __launch_bounds__(1024) void k_cellscan(const int* __restrict__ hist, int* __restrict__ rp) {
  __shared__ int part[1024];
  const int TOT = 2 * NCELL;  // 5000
  int t = threadIdx.x;
  int beg = t * 5, end = beg + 5;
  if (beg > TOT) beg = TOT;
  if (end > TOT) end = TOT;
  int s = 0;
  for (int i = beg; i < end; ++i) s += hist[i];
  part[t] = s;
  __syncthreads();
  for (int o = 1; o < 1024; o <<= 1) {
    int v = part[t];
    int u = (t >= o) ? part[t - o] : 0;
    __syncthreads();
    part[t] = v + u;
    __syncthreads();
  }
  int base = (t > 0) ? part[t - 1] : 0;
  for (int i = beg; i < end; ++i) { rp[i] = base; base += hist[i]; }
  if (t == 1023) rp[TOT] = part[1023];
}

__global__ __launch_bounds__(256) void k_cellscatter(const float2* __restrict__ apos,
                                                     const float2* __restrict__ tpos,
                                                     const int* __restrict__ rp, int* __restrict__ cur,
                                                     float2* __restrict__ ps, int* __restrict__ pid) {
  int i = blockIdx.x * 256 + threadIdx.x;
  if (i >= 2 * NA) return;
  int graph = (i >= NA) ? 1 : 0;
  int idx = i - graph * NA;
  float2 p = graph ? tpos[idx] : apos[idx];
  int gc = graph * NCELL + cell_of(p);
  int o = rp[gc] + atomicAdd(&cur[gc], 1);
  ps[o] = p;
  pid[o] = idx;
}

// ---------------- binned neighbor search: exact top-10 within radius ----------------
__global__ __launch_bounds__(256) void k_nbr2(const float2* __restrict__ apos,
                                              const int* __restrict__ rp,
                                              const float2* __restrict__ ps, const int* __restrict__ pid,
                                              int* __restrict__ a_idx, int* __restrict__ a_cnt,
                                              int* __restrict__ t_idx, int* __restrict__ t_cnt) {
  int tid = blockIdx.x * 256 + threadIdx.x;
  if (tid >= 2 * NA) return;
  int graph = (tid >= NA) ? 1 : 0;
  int q = tid - graph * NA;
  float2 qp = apos[q];
  int cx = min(max((int)(qp.x * 0.5f), 0), GRID - 1);
  int cy = min(max((int)(qp.y * 0.5f), 0), GRID - 1);

  u64 top[10];
#pragma unroll
  for (int t = 0; t < 10; ++t) top[t] = ~0ull;

  int x0 = max(cx - 1, 0), x1 = min(cx + 1, GRID - 1);
  int y0 = max(cy - 1, 0), y1 = min(cy + 1, GRID - 1);
  for (int yy = y0; yy <= y1; ++yy) {
    int cb = graph * NCELL + yy * GRID + x0;
    int ce = graph * NCELL + yy * GRID + x1;
    int b = rp[cb], e = rp[ce + 1];   // contiguous cells -> contiguous points
    for (int j = b; j < e; ++j) {
      float2 kp = ps[j];
      float dx = qp.x - kp.x;
      float dy = qp.y - kp.y;
      float d2 = __fadd_rn(__fmul_rn(dx, dx), __fmul_rn(dy, dy));
      int g = pid[j];
      if (d2 <= 4.0f && !(graph == 0 && g == q)) {
        u64 key = ((u64)__float_as_uint(d2) << 32) | (u32)g;
        if (key < top[9]) insert10(top, key);
      }
    }
  }
  int cnt = 0;
#pragma unroll
  for (int t = 0; t < 10; ++t) cnt += (top[t] != ~0ull) ? 1 : 0;
  int* oi = graph ? t_idx : a_idx;
#pragma unroll
  for (int t = 0; t < 10; ++t) oi[(size_t)q * 10 + t] = (int)(u32)(top[t] & 0xffffffffu);
  if (graph) t_cnt[q] = cnt; else a_cnt[q] = cnt;
}

// ---------------- GATv2 (32 channels, K<=10), fully unrolled ----------------
__device__ __forceinline__ void gat32(float qx, float qy,
                                      const float2* __restrict__ srcpos,
                                      const int* __restrict__ idxlist, int cnt,
                                      const float* __restrict__ Wl, const float* __restrict__ Wr,
                                      const float* __restrict__ att, const float* __restrict__ bb,
                                      float* __restrict__ out) {
  float xr[32];
#pragma unroll
  for (int c = 0; c < 32; ++c) xr[c] = qx * Wr[c] + qy * Wr[32 + c];
  float pjx[10], pjy[10], pv[10];
  float m = -1e30f;
#pragma unroll
  for (int k = 0; k < 10; ++k) {
    bool valid = (k < cnt);
    int j = valid ? idxlist[k] : 0;
    float2 p = srcpos[j];
    pjx[k] = p.x; pjy[k] = p.y;
    float sacc = 0.f;
#pragma unroll
    for (int c = 0; c < 32; ++c) {
      float xl = p.x * Wl[c] + p.y * Wl[32 + c];
      float g = xl + xr[c];
      g = (g >= 0.f) ? g : 0.2f * g;
      sacc += att[c] * g;
    }
    pv[k] = sacc;
    m = valid ? fmaxf(m, sacc) : m;
  }
  float sum = 0.f;
#pragma unroll
  for (int k = 0; k < 10; ++k) {
    float e = (k < cnt) ? expf(pv[k] - m) : 0.f;
    pv[k] = e;
    sum += e;
  }
  float inv = 1.f / (sum + 1e-16f);
#pragma unroll
  for (int c = 0; c < 32; ++c) out[c] = bb[c];
#pragma unroll
  for (int k = 0; k < 10; ++k) {
    float a = pv[k] * inv;
#pragma unroll
    for (int c = 0; c < 32; ++c) {
      float xl = pjx[k] * Wl[c] + pjy[k] * Wl[32 + c];
      out[c] += a * xl;
    }
  }
}

__global__ __launch_bounds__(256) void k_buildx(
    const float* __restrict__ own_obs, const float2* __restrict__ apos, const float2* __restrict__ tpos,
    const float* __restrict__ W_self, const float* __restrict__ b_self,
    const float* __restrict__ agWl, const float* __restrict__ agWr,
    const float* __restrict__ agatt, const float* __restrict__ agb,
    const float* __restrict__ tgWl, const float* __restrict__ tgWr,
    const float* __restrict__ tgatt, const float* __restrict__ tgb,
    const int* __restrict__ a_idx, const int* __restrict__ a_cnt,
    const int* __restrict__ t_idx, const int* __restrict__ t_cnt,
    float* __restrict__ x) {
  __shared__ float sW[512], sb[64];
  __shared__ float sagWl[64], sagWr[64], sagatt[32], sagb[32];
  __shared__ float stgWl[64], stgWr[64], stgatt[32], stgb[32];
  int t = threadIdx.x;
  for (int i = t; i < 512; i += 256) sW[i] = W_self[i];
  if (t < 64) { sb[t] = b_self[t]; sagWl[t] = agWl[t]; sagWr[t] = agWr[t]; stgWl[t] = tgWl[t]; stgWr[t] = tgWr[t]; }
  if (t < 32) { sagatt[t] = agatt[t]; sagb[t] = agb[t]; stgatt[t] = tgatt[t]; stgb[t] = tgb[t]; }
  __syncthreads();
  int q = blockIdx.x * 256 + t;
  if (q >= NA) return;

  const float4* op = (const float4*)(own_obs + (size_t)q * 8);
  float4 o0 = op[0], o1 = op[1];
  float obs[8] = {o0.x, o0.y, o0.z, o0.w, o1.x, o1.y, o1.z, o1.w};
  float* xrow = x + (size_t)q * 128;
#pragma unroll
  for (int c4 = 0; c4 < 16; ++c4) {
    float4 v;
    float* vp = (float*)&v;
#pragma unroll
    for (int jj = 0; jj < 4; ++jj) {
      int c = c4 * 4 + jj;
      float s = sb[c];
#pragma unroll
      for (int i = 0; i < 8; ++i) s += obs[i] * sW[i * 64 + c];
      vp[jj] = s;
    }
    *(float4*)(xrow + c4 * 4) = v;
  }

  float2 qp = apos[q];
  float outA[32];
  gat32(qp.x, qp.y, apos, a_idx + (size_t)q * 10, a_cnt[q], sagWl, sagWr, sagatt, sagb, outA);
#pragma unroll
  for (int c4 = 0; c4 < 8; ++c4)
    *(float4*)(xrow + 64 + c4 * 4) = make_float4(outA[c4 * 4], outA[c4 * 4 + 1], outA[c4 * 4 + 2], outA[c4 * 4 + 3]);

  float outT[32];
  gat32(qp.x, qp.y, tpos, t_idx + (size_t)q * 10, t_cnt[q], stgWl, stgWr, stgatt, stgb, outT);
#pragma unroll
  for (int c4 = 0; c4 < 8; ++c4)
    *(float4*)(xrow + 96 + c4 * 4) = make_float4(outT[c4 * 4], outT[c4 * 4 + 1], outT[c4 * 4 + 2], outT[c4 * 4 + 3]);
}

// ---------------- CSR build ----------------
__global__ __launch_bounds__(256) void k_hist(const int* __restrict__ edst, int* __restrict__ deg) {
  int e = blockIdx.x * 256 + threadIdx.x;
  if (e < NE) atomicAdd(&deg[edst[e]], 1);
}

__global__ __launch_bounds__(1024) void k_scan(const int* __restrict__ deg, int* __restrict__ rp) {
  __shared__ int part[1024];
  int t = threadIdx.x;
  int beg = t * 10, end = beg + 10;
  if (end > NA) end = NA;
  if (beg > NA) beg = NA;
  int s = 0;
  for (int i = beg; i < end; ++i) s += deg[i];
  part[t] = s;
  __syncthreads();
  for (int o = 1; o < 1024; o <<= 1) {
    int v = part[t];
    int u = (t >= o) ? part[t - o] : 0;
    __syncthreads();
    part[t] = v + u;
    __syncthreads();
  }
  int base = (t > 0) ? part[t - 1] : 0;
  for (int i = beg; i < end; ++i) { rp[i] = base; base += deg[i]; }
  if (t == 1023) rp[NA] = part[1023];
}

__global__ __launch_bounds__(256) void k_scatter(const int* __restrict__ esrc, const int* __restrict__ edst,
                                                 const int* __restrict__ rp, int* __restrict__ cur,
                                                 int* __restrict__ col) {
  int e = blockIdx.x * 256 + threadIdx.x;
  if (e < NE) {
    int d = edst[e];
    int p = atomicAdd(&cur[d], 1);
    col[rp[d] + p] = esrc[e];
  }
}

// ---------------- one adjacency shift: xout[d] = sum_{e:dst=d} xin[src_e] ----------------
__global__ __launch_bounds__(256) void k_shift(const float* __restrict__ xin, float* __restrict__ xout,
                                               const int* __restrict__ rp, const int* __restrict__ col) {
  int w = blockIdx.x * 4 + (threadIdx.x >> 6);
  int lane = threadIdx.x & 63;
  if (w >= NA) return;
  int beg = rp[w], end = rp[w + 1];
  const float2* xin2 = (const float2*)xin;
  float2 acc = make_float2(0.f, 0.f);
  int j = beg;
  for (; j + 1 < end; j += 2) {
    int s0 = col[j], s1 = col[j + 1];
    float2 v0 = xin2[(size_t)s0 * 64 + lane];
    float2 v1 = xin2[(size_t)s1 * 64 + lane];
    acc.x += v0.x; acc.y += v0.y;
    acc.x += v1.x; acc.y += v1.y;
  }
  if (j < end) {
    int s0 = col[j];
    float2 v0 = xin2[(size_t)s0 * 64 + lane];
    acc.x += v0.x; acc.y += v0.y;
  }
  ((float2*)xout)[(size_t)w * 64 + lane] = acc;
}

// ---------------- fused 4-tap GEMM: y = b + sum_t xs_t @ W_t ----------------
__device__ __forceinline__ void gemm_tap(const float* __restrict__ xptr, const float* __restrict__ Wt,
                                         float (*xs)[128], float acc[4][4], int rowbase, int rgrp, int c0) {
  __syncthreads();
  for (int tt = threadIdx.x; tt < 1024; tt += 256) {
    int r = tt >> 5, cq = tt & 31;
    int gr = rowbase + r;
    float4 v = make_float4(0.f, 0.f, 0.f, 0.f);
    if (gr < NA) v = *(const float4*)(xptr + (size_t)gr * 128 + cq * 4);
    *(float4*)(&xs[r][cq * 4]) = v;
  }
  __syncthreads();
#pragma unroll 4
  for (int k = 0; k < 128; ++k) {
    float4 wv = *(const float4*)(Wt + k * 128 + c0);
    float a0 = xs[rgrp * 4 + 0][k];
    float a1 = xs[rgrp * 4 + 1][k];
    float a2 = xs[rgrp * 4 + 2][k];
    float a3 = xs[rgrp * 4 + 3][k];
    acc[0][0] += a0 * wv.x; acc[0][1] += a0 * wv.y; acc[0][2] += a0 * wv.z; acc[0][3] += a0 * wv.w;
    acc[1][0] += a1 * wv.x; acc[1][1] += a1 * wv.y; acc[1][2] += a1 * wv.z; acc[1][3] += a1 * wv.w;
    acc[2][0] += a2 * wv.x; acc[2][1] += a2 * wv.y; acc[2][2] += a2 * wv.z; acc[2][3] += a2 * wv.w;
    acc[3][0] += a3 * wv.x; acc[3][1] += a3 * wv.y; acc[3][2] += a3 * wv.z; acc[3][3] += a3 * wv.w;
  }
}

__global__ __launch_bounds__(256) void k_gemm4(const float* __restrict__ x0, const float* __restrict__ x1,
                                               const float* __restrict__ x2, const float* __restrict__ x3,
                                               const float* __restrict__ W, const float* __restrict__ b,
                                               float* __restrict__ y) {
  __shared__ float xs[32][128];
  const int rgrp = threadIdx.x >> 5;
  const int cgrp = threadIdx.x & 31;
  const int c0 = cgrp * 4;
  const int rowbase = blockIdx.x * 32;
  float acc[4][4];
  float4 bb = *(const float4*)(b + c0);
#pragma unroll
  for (int i = 0; i < 4; ++i) { acc[i][0] = bb.x; acc[i][1] = bb.y; acc[i][2] = bb.z; acc[i][3] = bb.w; }
  gemm_tap(x0, W, xs, acc, rowbase, rgrp, c0);
  gemm_tap(x1, W + 16384, xs, acc, rowbase, rgrp, c0);
  gemm_tap(x2, W + 32768, xs, acc, rowbase, rgrp, c0);
  gemm_tap(x3, W + 49152, xs, acc, rowbase, rgrp, c0);
#pragma unroll
  for (int i = 0; i < 4; ++i) {
    int r = rowbase + rgrp * 4 + i;
    if (r < NA) *(float4*)(y + (size_t)r * 128 + c0) = make_float4(acc[i][0], acc[i][1], acc[i][2], acc[i][3]);
  }
}

// ---------------- BatchNorm ----------------
__global__ __launch_bounds__(256) void k_bnred(const float* __restrict__ y, double* __restrict__ stats) {
  int c = threadIdx.x & 127;
  int slice = blockIdx.x * 2 + (threadIdx.x >> 7);
  double s = 0.0, ss = 0.0;
  for (int r = slice; r < NA; r += 128) {
    double v = (double)y[(size_t)r * 128 + c];
    s += v;
    ss += v * v;
  }
  atomicAdd(&stats[c], s);
  atomicAdd(&stats[128 + c], ss);
}

__global__ void k_bnfin(const double* __restrict__ stats, const float* __restrict__ gamma,
                        const float* __restrict__ beta, float* __restrict__ AB) {
  int c = threadIdx.x;
  double mu = stats[c] / (double)NA;
  double var = stats[128 + c] / (double)NA - mu * mu;
  double rs = 1.0 / sqrt(var + 1e-5);
  float A = (float)rs * gamma[c];
  float B = beta[c] - (float)(mu * rs) * gamma[c];
  AB[c] = A;
  AB[128 + c] = B;
}

__global__ __launch_bounds__(256) void k_bnapply(const float* __restrict__ y, const float* __restrict__ AB,
                                                 float* __restrict__ x) {
  int i = blockIdx.x * 256 + threadIdx.x;
  int c = i & 127;
  float v = y[i] * AB[c] + AB[128 + c];
  v = (v >= 0.f) ? v : 0.01f * v;
  x[i] += v;
}

// ---------------- readout ----------------
__global__ __launch_bounds__(256) void k_read(const float* __restrict__ x, const float* __restrict__ Wr,
                                              const float* __restrict__ br, float* __restrict__ out) {
  int q = blockIdx.x * 256 + threadIdx.x;
  if (q >= NA) return;
  float a0 = br[0], a1 = br[1];
  const float* xr = x + (size_t)q * 128;
#pragma unroll 8
  for (int c = 0; c < 128; ++c) {
    float v = xr[c];
    a0 += v * Wr[c * 2 + 0];
    a1 += v * Wr[c * 2 + 1];
  }
  out[q * 2 + 0] = a0;
  out[q * 2 + 1] = a1;
}

extern "C" void kernel_launch(void* const* d_in, const int* in_sizes, int n_in,
                              void* d_out, int out_size, void* d_ws, size_t ws_size,
                              hipStream_t stream) {
  (void)in_sizes; (void)n_in; (void)out_size; (void)ws_size;
  const float* own_obs = (const float*)d_in[0];
  const float2* apos = (const float2*)d_in[1];
  const float2* tpos = (const float2*)d_in[2];
  const float* W_self = (const float*)d_in[3];
  const float* b_self = (const float*)d_in[4];
  const float* agWl = (const float*)d_in[5];
  const float* agWr = (const float*)d_in[6];
  const float* agatt = (const float*)d_in[7];
  const float* agb = (const float*)d_in[8];
  const float* tgWl = (const float*)d_in[9];
  const float* tgWr = (const float*)d_in[10];
  const float* tgatt = (const float*)d_in[11];
  const float* tgb = (const float*)d_in[12];
  const float* gfW = (const float*)d_in[13];
  const float* gfb = (const float*)d_in[14];
  const float* bng = (const float*)d_in[15];
  const float* bnb = (const float*)d_in[16];
  const float* Wread = (const float*)d_in[17];
  const float* bread = (const float*)d_in[18];
  const int* ei = (const int*)d_in[19];
  const int* esrc = ei;
  const int* edst = ei + NE;

  char* w = (char*)d_ws;
  size_t off = 0;
  auto take = [&](size_t bytes) -> void* {
    void* p = w + off;
    off += (bytes + 255) & ~(size_t)255;
    return p;
  };
  int* a_idx = (int*)take((size_t)NA * KN * 4);
  int* t_idx = (int*)take((size_t)NA * KN * 4);
  int* a_cnt = (int*)take((size_t)NA * 4);
  int* t_cnt = (int*)take((size_t)NA * 4);
  float* x = (float*)take((size_t)NA * 128 * 4);
  float* y = (float*)take((size_t)NA * 128 * 4);
  float* sh1 = (float*)take((size_t)NA * 128 * 4);
  float* sh2 = (float*)take((size_t)NA * 128 * 4);
  float* sh3 = (float*)take((size_t)NA * 128 * 4);
  double* stats = (double*)take(256 * 8 + 256 * 4);  // 256 doubles + 256 floats (A,B)
  float* AB = (float*)(stats + 256);
  int* deg = (int*)take((size_t)NA * 4);
  int* rp = (int*)take((size_t)(NA + 1) * 4);
  int* col = (int*)take((size_t)NE * 4);
  int* chist = (int*)take((size_t)2 * NCELL * 4);
  int* crp = (int*)take((size_t)(2 * NCELL + 1) * 4);
  int* ccur = (int*)take((size_t)2 * NCELL * 4);
  float2* ps = (float2*)take((size_t)2 * NA * 8);
  int* pid = (int*)take((size_t)2 * NA * 4);

  // edge CSR build
  hipMemsetAsync(deg, 0, (size_t)NA * 4, stream);
  k_hist<<<(NE + 255) / 256, 256, 0, stream>>>(edst, deg);
  k_scan<<<1, 1024, 0, stream>>>(deg, rp);
  hipMemsetAsync(deg, 0, (size_t)NA * 4, stream);
  k_scatter<<<(NE + 255) / 256, 256, 0, stream>>>(esrc, edst, rp, deg, col);

  // binned neighbor search
  hipMemsetAsync(chist, 0, (size_t)2 * NCELL * 4, stream);
  hipMemsetAsync(ccur, 0, (size_t)2 * NCELL * 4, stream);
  k_cellhist<<<(2 * NA + 255) / 256, 256, 0, stream>>>(apos, tpos, chist);
  k_cellscan<<<1, 1024, 0, stream>>>(chist, crp);
  k_cellscatter<<<(2 * NA + 255) / 256, 256, 0, stream>>>(apos, tpos, crp, ccur, ps, pid);
  k_nbr2<<<(2 * NA + 255) / 256, 256, 0, stream>>>(apos, crp, ps, pid, a_idx, a_cnt, t_idx, t_cnt);

  // build x = [self | gat_a | gat_t]
  k_buildx<<<(NA + 255) / 256, 256, 0, stream>>>(own_obs, apos, tpos, W_self, b_self,
                                                 agWl, agWr, agatt, agb, tgWl, tgWr, tgatt, tgb,
                                                 a_idx, a_cnt, t_idx, t_cnt, x);

  // two graph-filter + BN + residual layers
  for (int l = 0; l < 2; ++l) {
    const float* Wl = gfW + (size_t)l * 4 * 128 * 128;
    const float* bl = gfb + (size_t)l * 128;
    const float* gl = bng + (size_t)l * 128;
    const float* bb = bnb + (size_t)l * 128;
    k_shift<<<NA / 4, 256, 0, stream>>>(x, sh1, rp, col);
    k_shift<<<NA / 4, 256, 0, stream>>>(sh1, sh2, rp, col);
    k_shift<<<NA / 4, 256, 0, stream>>>(sh2, sh3, rp, col);
    k_gemm4<<<(NA + 31) / 32, 256, 0, stream>>>(x, sh1, sh2, sh3, Wl, bl, y);
    hipMemsetAsync(stats, 0, 256 * 8, stream);
    k_bnred<<<64, 256, 0, stream>>>(y, stats);
    k_bnfin<<<1, 128, 0, stream>>>(stats, gl, bb, AB);
    k_bnapply<<<(NA * 128) / 256, 256, 0, stream>>>(y, AB, x);
  }

  k_read<<<(NA + 255) / 256, 256, 0, stream>>>(x, Wread, bread, (float*)d_out);
}

// Round 4
// 395.414 us; speedup vs baseline: 1.6287x; 1.1458x over previous
//
#include <hip/hip_runtime.h>

typedef unsigned long long u64;
typedef unsigned int u32;
typedef unsigned short ushort_t;

#define NA 10000
#define NE 320000
#define KN 10
#define GRID 50
#define NCELL (GRID * GRID)      // 2500 cells of width 2.0 over [0,100)^2

typedef __attribute__((ext_vector_type(8))) short short8v;
typedef __attribute__((ext_vector_type(4))) float f32x4;

// ---------------- bf16 helpers (RNE) ----------------
__device__ __forceinline__ u32 f2bf(float f) {
  union { float f; u32 u; } v; v.f = f;
  return (v.u + 0x7fffu + ((v.u >> 16) & 1u)) >> 16;
}
__device__ __forceinline__ float bf2f(u32 b) {
  union { u32 u; float f; } v; v.u = b << 16;
  return v.f;
}

// ---------------- top-10 (d2,idx) maintenance ----------------
__device__ __forceinline__ void insert10(u64* top, u64 key) {
#pragma unroll
  for (int t = 9; t > 0; --t) {
    u64 prev = top[t - 1];
    u64 cur = top[t];
    top[t] = (key < prev) ? prev : ((key < cur) ? key : cur);
  }
  top[0] = (key < top[0]) ? key : top[0];
}

__device__ __forceinline__ int cell_of(float2 p) {
  int cx = (int)(p.x * 0.5f);            // exact: *0.5 is a pow2 multiply
  int cy = (int)(p.y * 0.5f);
  cx = min(max(cx, 0), GRID - 1);
  cy = min(max(cy, 0), GRID - 1);
  return cy * GRID + cx;
}

// ---------------- cell binning: hist / scan / scatter ----------------
__global__ __launch_bounds__(256) void k_cellhist(const float2* __restrict__ apos,
                                                  const float2* __restrict__ tpos,
                                                  int* __restrict__ hist) {
  int i = blockIdx.x * 256 + threadIdx.x;
  if (i >= 2 * NA) return;
  int graph = (i >= NA) ? 1 : 0;
  int idx = i - graph * NA;
  float2 p = graph ? tpos[idx] : apos[idx];
  atomicAdd(&hist[graph * NCELL + cell_of(p)], 1);
}

__global__ __launch_bounds__(1024) void k_cellscan(const int* __restrict__ hist, int* __restrict__ rp) {
  __shared__ int part[1024];
  const int TOT = 2 * NCELL;  // 5000
  int t = threadIdx.x;
  int beg = t * 5, end = beg + 5;
  if (beg > TOT) beg = TOT;
  if (end > TOT) end = TOT;
  int s = 0;
  for (int i = beg; i < end; ++i) s += hist[i];
  part[t] = s;
  __syncthreads();
  for (int o = 1; o < 1024; o <<= 1) {
    int v = part[t];
    int u = (t >= o) ? part[t - o] : 0;
    __syncthreads();
    part[t] = v + u;
    __syncthreads();
  }
  int base = (t > 0) ? part[t - 1] : 0;
  for (int i = beg; i < end; ++i) { rp[i] = base; base += hist[i]; }
  if (t == 1023) rp[TOT] = part[1023];
}

__global__ __launch_bounds__(256) void k_cellscatter(const float2* __restrict__ apos,
                                                     const float2* __restrict__ tpos,
                                                     const int* __restrict__ rp, int* __restrict__ cur,
                                                     float2* __restrict__ ps, int* __restrict__ pid) {
  int i = blockIdx.x * 256 + threadIdx.x;
  if (i >= 2 * NA) return;
  int graph = (i >= NA) ? 1 : 0;
  int idx = i - graph * NA;
  float2 p = graph ? tpos[idx] : apos[idx];
  int gc = graph * NCELL + cell_of(p);
  int o = rp[gc] + atomicAdd(&cur[gc], 1);
  ps[o] = p;
  pid[o] = idx;
}

// ---------------- binned neighbor search: exact top-10 within radius ----------------
__global__ __launch_bounds__(256) void k_nbr2(const float2* __restrict__ apos,
                                              const int* __restrict__ rp,
                                              const float2* __restrict__ ps, const int* __restrict__ pid,
                                              int* __restrict__ a_idx, int* __restrict__ a_cnt,
                                              int* __restrict__ t_idx, int* __restrict__ t_cnt) {
  int tid = blockIdx.x * 256 + threadIdx.x;
  if (tid >= 2 * NA) return;
  int graph = (tid >= NA) ? 1 : 0;
  int q = tid - graph * NA;
  float2 qp = apos[q];
  int cx = min(max((int)(qp.x * 0.5f), 0), GRID - 1);
  int cy = min(max((int)(qp.y * 0.5f), 0), GRID - 1);

  u64 top[10];
#pragma unroll
  for (int t = 0; t < 10; ++t) top[t] = ~0ull;

  int x0 = max(cx - 1, 0), x1 = min(cx + 1, GRID - 1);
  int y0 = max(cy - 1, 0), y1 = min(cy + 1, GRID - 1);
  for (int yy = y0; yy <= y1; ++yy) {
    int cb = graph * NCELL + yy * GRID + x0;
    int ce = graph * NCELL + yy * GRID + x1;
    int b = rp[cb], e = rp[ce + 1];   // contiguous cells -> contiguous points
    for (int j = b; j < e; ++j) {
      float2 kp = ps[j];
      float dx = qp.x - kp.x;
      float dy = qp.y - kp.y;
      float d2 = __fadd_rn(__fmul_rn(dx, dx), __fmul_rn(dy, dy));
      int g = pid[j];
      if (d2 <= 4.0f && !(graph == 0 && g == q)) {
        u64 key = ((u64)__float_as_uint(d2) << 32) | (u32)g;
        if (key < top[9]) insert10(top, key);
      }
    }
  }
  int cnt = 0;
#pragma unroll
  for (int t = 0; t < 10; ++t) cnt += (top[t] != ~0ull) ? 1 : 0;
  int* oi = graph ? t_idx : a_idx;
#pragma unroll
  for (int t = 0; t < 10; ++t) oi[(size_t)q * 10 + t] = (int)(u32)(top[t] & 0xffffffffu);
  if (graph) t_cnt[q] = cnt; else a_cnt[q] = cnt;
}

// ---------------- GATv2 (32 channels, K<=10), fully unrolled ----------------
__device__ __forceinline__ void gat32(float qx, float qy,
                                      const float2* __restrict__ srcpos,
                                      const int* __restrict__ idxlist, int cnt,
                                      const float* __restrict__ Wl, const float* __restrict__ Wr,
                                      const float* __restrict__ att, const float* __restrict__ bb,
                                      float* __restrict__ out) {
  float xr[32];
#pragma unroll
  for (int c = 0; c < 32; ++c) xr[c] = qx * Wr[c] + qy * Wr[32 + c];
  float pjx[10], pjy[10], pv[10];
  float m = -1e30f;
#pragma unroll
  for (int k = 0; k < 10; ++k) {
    bool valid = (k < cnt);
    int j = valid ? idxlist[k] : 0;
    float2 p = srcpos[j];
    pjx[k] = p.x; pjy[k] = p.y;
    float sacc = 0.f;
#pragma unroll
    for (int c = 0; c < 32; ++c) {
      float xl = p.x * Wl[c] + p.y * Wl[32 + c];
      float g = xl + xr[c];
      g = (g >= 0.f) ? g : 0.2f * g;
      sacc += att[c] * g;
    }
    pv[k] = sacc;
    m = valid ? fmaxf(m, sacc) : m;
  }
  float sum = 0.f;
#pragma unroll
  for (int k = 0; k < 10; ++k) {
    float e = (k < cnt) ? expf(pv[k] - m) : 0.f;
    pv[k] = e;
    sum += e;
  }
  float inv = 1.f / (sum + 1e-16f);
#pragma unroll
  for (int c = 0; c < 32; ++c) out[c] = bb[c];
#pragma unroll
  for (int k = 0; k < 10; ++k) {
    float a = pv[k] * inv;
#pragma unroll
    for (int c = 0; c < 32; ++c) {
      float xl = pjx[k] * Wl[c] + pjy[k] * Wl[32 + c];
      out[c] += a * xl;
    }
  }
}

__global__ __launch_bounds__(256) void k_buildx(
    const float* __restrict__ own_obs, const float2* __restrict__ apos, const float2* __restrict__ tpos,
    const float* __restrict__ W_self, const float* __restrict__ b_self,
    const float* __restrict__ agWl, const float* __restrict__ agWr,
    const float* __restrict__ agatt, const float* __restrict__ agb,
    const float* __restrict__ tgWl, const float* __restrict__ tgWr,
    const float* __restrict__ tgatt, const float* __restrict__ tgb,
    const int* __restrict__ a_idx, const int* __restrict__ a_cnt,
    const int* __restrict__ t_idx, const int* __restrict__ t_cnt,
    float* __restrict__ x) {
  __shared__ float sW[512], sb[64];
  __shared__ float sagWl[64], sagWr[64], sagatt[32], sagb[32];
  __shared__ float stgWl[64], stgWr[64], stgatt[32], stgb[32];
  int t = threadIdx.x;
  for (int i = t; i < 512; i += 256) sW[i] = W_self[i];
  if (t < 64) { sb[t] = b_self[t]; sagWl[t] = agWl[t]; sagWr[t] = agWr[t]; stgWl[t] = tgWl[t]; stgWr[t] = tgWr[t]; }
  if (t < 32) { sagatt[t] = agatt[t]; sagb[t] = agb[t]; stgatt[t] = tgatt[t]; stgb[t] = tgb[t]; }
  __syncthreads();
  int q = blockIdx.x * 256 + t;
  if (q >= NA) return;

  const float4* op = (const float4*)(own_obs + (size_t)q * 8);
  float4 o0 = op[0], o1 = op[1];
  float obs[8] = {o0.x, o0.y, o0.z, o0.w, o1.x, o1.y, o1.z, o1.w};
  float* xrow = x + (size_t)q * 128;
#pragma unroll
  for (int c4 = 0; c4 < 16; ++c4) {
    float4 v;
    float* vp = (float*)&v;
#pragma unroll
    for (int jj = 0; jj < 4; ++jj) {
      int c = c4 * 4 + jj;
      float s = sb[c];
#pragma unroll
      for (int i = 0; i < 8; ++i) s += obs[i] * sW[i * 64 + c];
      vp[jj] = s;
    }
    *(float4*)(xrow + c4 * 4) = v;
  }

  float2 qp = apos[q];
  float outA[32];
  gat32(qp.x, qp.y, apos, a_idx + (size_t)q * 10, a_cnt[q], sagWl, sagWr, sagatt, sagb, outA);
#pragma unroll
  for (int c4 = 0; c4 < 8; ++c4)
    *(float4*)(xrow + 64 + c4 * 4) = make_float4(outA[c4 * 4], outA[c4 * 4 + 1], outA[c4 * 4 + 2], outA[c4 * 4 + 3]);

  float outT[32];
  gat32(qp.x, qp.y, tpos, t_idx + (size_t)q * 10, t_cnt[q], stgWl, stgWr, stgatt, stgb, outT);
#pragma unroll
  for (int c4 = 0; c4 < 8; ++c4)
    *(float4*)(xrow + 96 + c4 * 4) = make_float4(outT[c4 * 4], outT[c4 * 4 + 1], outT[c4 * 4 + 2], outT[c4 * 4 + 3]);
}

// ---------------- CSR build ----------------
__global__ __launch_bounds__(256) void k_hist(const int* __restrict__ edst, int* __restrict__ deg) {
  int e = blockIdx.x * 256 + threadIdx.x;
  if (e < NE) atomicAdd(&deg[edst[e]], 1);
}

__global__ __launch_bounds__(1024) void k_scan(const int* __restrict__ deg, int* __restrict__ rp) {
  __shared__ int part[1024];
  int t = threadIdx.x;
  int beg = t * 10, end = beg + 10;
  if (end > NA) end = NA;
  if (beg > NA) beg = NA;
  int s = 0;
  for (int i = beg; i < end; ++i) s += deg[i];
  part[t] = s;
  __syncthreads();
  for (int o = 1; o < 1024; o <<= 1) {
    int v = part[t];
    int u = (t >= o) ? part[t - o] : 0;
    __syncthreads();
    part[t] = v + u;
    __syncthreads();
  }
  int base = (t > 0) ? part[t - 1] : 0;
  for (int i = beg; i < end; ++i) { rp[i] = base; base += deg[i]; }
  if (t == 1023) rp[NA] = part[1023];
}

__global__ __launch_bounds__(256) void k_scatter(const int* __restrict__ esrc, const int* __restrict__ edst,
                                                 const int* __restrict__ rp, int* __restrict__ cur,
                                                 int* __restrict__ col) {
  int e = blockIdx.x * 256 + threadIdx.x;
  if (e < NE) {
    int d = edst[e];
    int p = atomicAdd(&cur[d], 1);
    col[rp[d] + p] = esrc[e];
  }
}

// ---------------- one adjacency shift (f32): xout[d] = sum_{e:dst=d} xin[src_e] ----------------
__global__ __launch_bounds__(256) void k_shift(const float* __restrict__ xin, float* __restrict__ xout,
                                               const int* __restrict__ rp, const int* __restrict__ col) {
  int w = blockIdx.x * 4 + (threadIdx.x >> 6);
  int lane = threadIdx.x & 63;
  if (w >= NA) return;
  int beg = rp[w], end = rp[w + 1];
  const float2* xin2 = (const float2*)xin;
  float2 acc = make_float2(0.f, 0.f);
  int j = beg;
  for (; j + 1 < end; j += 2) {
    int s0 = col[j], s1 = col[j + 1];
    float2 v0 = xin2[(size_t)s0 * 64 + lane];
    float2 v1 = xin2[(size_t)s1 * 64 + lane];
    acc.x += v0.x; acc.y += v0.y;
    acc.x += v1.x; acc.y += v1.y;
  }
  if (j < end) {
    int s0 = col[j];
    float2 v0 = xin2[(size_t)s0 * 64 + lane];
    acc.x += v0.x; acc.y += v0.y;
  }
  ((float2*)xout)[(size_t)w * 64 + lane] = acc;
}

// ---------------- W repack: f32 [l][t][k][n] -> bf16 hi/lo B-frag layout [l][t][kt][ct][lane][8] ----------------
__global__ __launch_bounds__(256) void k_packw(const float* __restrict__ gfW,
                                               ushort_t* __restrict__ Wh, ushort_t* __restrict__ Wlo) {
  int tid = blockIdx.x * 256 + threadIdx.x;   // 2*4*128*128 = 131072
  if (tid >= 131072) return;
  int l = tid >> 16;
  int rem = tid & 65535;
  int t = rem >> 14;
  int k = (rem >> 7) & 127;
  int n = rem & 127;
  float v = gfW[(size_t)tid];                 // gfW is [l][t][k][n] row-major contiguous
  int kt = k >> 5;
  int hi = (k >> 3) & 3;
  int j = k & 7;
  int ct = n >> 4;
  int lane = hi * 16 + (n & 15);
  size_t dst = (((((size_t)(l * 4 + t) * 4 + kt) * 8 + ct) * 64 + lane) * 8 + j);
  u32 h = f2bf(v);
  float r = v - bf2f(h);
  Wh[dst] = (ushort_t)h;
  Wlo[dst] = (ushort_t)f2bf(r);
}

// ---------------- MFMA 4-tap GEMM, bf16x3 split precision (f32 inputs, ~f32 accuracy) ----------------
__global__ __launch_bounds__(256) void k_gemm_mfma3(const float* __restrict__ a0, const float* __restrict__ a1,
                                                    const float* __restrict__ a2, const float* __restrict__ a3,
                                                    const ushort_t* __restrict__ Wh, const ushort_t* __restrict__ Wlo,
                                                    const float* __restrict__ b, float* __restrict__ y) {
  const int lane = threadIdx.x & 63;
  const int wave = threadIdx.x >> 6;          // 0..3
  const int ct0 = wave * 2;
  const int row = lane & 15;
  const int hi = lane >> 4;
  const int rb = blockIdx.x * 16;             // 625 blocks * 16 rows = 10000

  f32x4 acc[2];
#pragma unroll
  for (int c = 0; c < 2; ++c) {
    float bv = b[(ct0 + c) * 16 + row];       // D col = lane&15
    acc[c][0] = bv; acc[c][1] = bv; acc[c][2] = bv; acc[c][3] = bv;
  }

  const float* aps[4] = {a0, a1, a2, a3};
#pragma unroll
  for (int t = 0; t < 4; ++t) {
    const float* at = aps[t];
#pragma unroll
    for (int kt = 0; kt < 4; ++kt) {
      const float* ap = at + (size_t)(rb + row) * 128 + kt * 32 + hi * 8;
      float4 fa = *(const float4*)(ap);
      float4 fb = *(const float4*)(ap + 4);
      float av[8] = {fa.x, fa.y, fa.z, fa.w, fb.x, fb.y, fb.z, fb.w};
      short8v ah, al;
#pragma unroll
      for (int j = 0; j < 8; ++j) {
        u32 h = f2bf(av[j]);
        float r = av[j] - bf2f(h);
        ah[j] = (short)h;
        al[j] = (short)f2bf(r);
      }
#pragma unroll
      for (int c = 0; c < 2; ++c) {
        size_t widx = ((((size_t)t * 4 + kt) * 8 + (ct0 + c)) * 64 + lane) * 8;
        short8v bh = *(const short8v*)(Wh + widx);
        short8v bl = *(const short8v*)(Wlo + widx);
        acc[c] = __builtin_amdgcn_mfma_f32_16x16x32_bf16(ah, bh, acc[c], 0, 0, 0);
        acc[c] = __builtin_amdgcn_mfma_f32_16x16x32_bf16(al, bh, acc[c], 0, 0, 0);
        acc[c] = __builtin_amdgcn_mfma_f32_16x16x32_bf16(ah, bl, acc[c], 0, 0, 0);
      }
    }
  }

#pragma unroll
  for (int c = 0; c < 2; ++c) {
#pragma unroll
    for (int r = 0; r < 4; ++r) {
      int grow = rb + hi * 4 + r;             // D row = (lane>>4)*4 + reg
      y[(size_t)grow * 128 + (ct0 + c) * 16 + row] = acc[c][r];
    }
  }
}

// ---------------- BatchNorm ----------------
__global__ __launch_bounds__(256) void k_bnred(const float* __restrict__ y, double* __restrict__ stats) {
  int c = threadIdx.x & 127;
  int slice = blockIdx.x * 2 + (threadIdx.x >> 7);
  double s = 0.0, ss = 0.0;
  for (int r = slice; r < NA; r += 128) {
    double v = (double)y[(size_t)r * 128 + c];
    s += v;
    ss += v * v;
  }
  atomicAdd(&stats[c], s);
  atomicAdd(&stats[128 + c], ss);
}

__global__ void k_bnfin(const double* __restrict__ stats, const float* __restrict__ gamma,
                        const float* __restrict__ beta, float* __restrict__ AB) {
  int c = threadIdx.x;
  double mu = stats[c] / (double)NA;
  double var = stats[128 + c] / (double)NA - mu * mu;
  double rs = 1.0 / sqrt(var + 1e-5);
  float A = (float)rs * gamma[c];
  float B = beta[c] - (float)(mu * rs) * gamma[c];
  AB[c] = A;
  AB[128 + c] = B;
}

__global__ __launch_bounds__(256) void k_bnapply(const float* __restrict__ y, const float* __restrict__ AB,
                                                 float* __restrict__ x) {
  int i = blockIdx.x * 256 + threadIdx.x;
  int c = i & 127;
  float v = y[i] * AB[c] + AB[128 + c];
  v = (v >= 0.f) ? v : 0.01f * v;
  x[i] += v;
}

// ---------------- readout ----------------
__global__ __launch_bounds__(256) void k_read(const float* __restrict__ x, const float* __restrict__ Wr,
                                              const float* __restrict__ br, float* __restrict__ out) {
  int q = blockIdx.x * 256 + threadIdx.x;
  if (q >= NA) return;
  float a0 = br[0], a1 = br[1];
  const float* xr = x + (size_t)q * 128;
#pragma unroll 8
  for (int c = 0; c < 128; ++c) {
    float v = xr[c];
    a0 += v * Wr[c * 2 + 0];
    a1 += v * Wr[c * 2 + 1];
  }
  out[q * 2 + 0] = a0;
  out[q * 2 + 1] = a1;
}

extern "C" void kernel_launch(void* const* d_in, const int* in_sizes, int n_in,
                              void* d_out, int out_size, void* d_ws, size_t ws_size,
                              hipStream_t stream) {
  (void)in_sizes; (void)n_in; (void)out_size; (void)ws_size;
  const float* own_obs = (const float*)d_in[0];
  const float2* apos = (const float2*)d_in[1];
  const float2* tpos = (const float2*)d_in[2];
  const float* W_self = (const float*)d_in[3];
  const float* b_self = (const float*)d_in[4];
  const float* agWl = (const float*)d_in[5];
  const float* agWr = (const float*)d_in[6];
  const float* agatt = (const float*)d_in[7];
  const float* agb = (const float*)d_in[8];
  const float* tgWl = (const float*)d_in[9];
  const float* tgWr = (const float*)d_in[10];
  const float* tgatt = (const float*)d_in[11];
  const float* tgb = (const float*)d_in[12];
  const float* gfW = (const float*)d_in[13];
  const float* gfb = (const float*)d_in[14];
  const float* bng = (const float*)d_in[15];
  const float* bnb = (const float*)d_in[16];
  const float* Wread = (const float*)d_in[17];
  const float* bread = (const float*)d_in[18];
  const int* ei = (const int*)d_in[19];
  const int* esrc = ei;
  const int* edst = ei + NE;

  char* w = (char*)d_ws;
  size_t off = 0;
  auto take = [&](size_t bytes) -> void* {
    void* p = w + off;
    off += (bytes + 255) & ~(size_t)255;
    return p;
  };
  int* a_idx = (int*)take((size_t)NA * KN * 4);
  int* t_idx = (int*)take((size_t)NA * KN * 4);
  int* a_cnt = (int*)take((size_t)NA * 4);
  int* t_cnt = (int*)take((size_t)NA * 4);
  float* x = (float*)take((size_t)NA * 128 * 4);
  float* y = (float*)take((size_t)NA * 128 * 4);
  float* sh1 = (float*)take((size_t)NA * 128 * 4);
  float* sh2 = (float*)take((size_t)NA * 128 * 4);
  float* sh3 = (float*)take((size_t)NA * 128 * 4);
  ushort_t* Wh = (ushort_t*)take((size_t)131072 * 2);
  ushort_t* Wlo = (ushort_t*)take((size_t)131072 * 2);
  double* stats = (double*)take(256 * 8 + 256 * 4);  // 256 doubles + 256 floats (A,B)
  float* AB = (float*)(stats + 256);
  int* deg = (int*)take((size_t)NA * 4);
  int* rp = (int*)take((size_t)(NA + 1) * 4);
  int* col = (int*)take((size_t)NE * 4);
  int* chist = (int*)take((size_t)2 * NCELL * 4);
  int* crp = (int*)take((size_t)(2 * NCELL + 1) * 4);
  int* ccur = (int*)take((size_t)2 * NCELL * 4);
  float2* ps = (float2*)take((size_t)2 * NA * 8);
  int* pid = (int*)take((size_t)2 * NA * 4);

  // edge CSR build
  hipMemsetAsync(deg, 0, (size_t)NA * 4, stream);
  k_hist<<<(NE + 255) / 256, 256, 0, stream>>>(edst, deg);
  k_scan<<<1, 1024, 0, stream>>>(deg, rp);
  hipMemsetAsync(deg, 0, (size_t)NA * 4, stream);
  k_scatter<<<(NE + 255) / 256, 256, 0, stream>>>(esrc, edst, rp, deg, col);

  // W repack to bf16 hi/lo B-frag layout
  k_packw<<<131072 / 256, 256, 0, stream>>>(gfW, Wh, Wlo);

  // binned neighbor search
  hipMemsetAsync(chist, 0, (size_t)2 * NCELL * 4, stream);
  hipMemsetAsync(ccur, 0, (size_t)2 * NCELL * 4, stream);
  k_cellhist<<<(2 * NA + 255) / 256, 256, 0, stream>>>(apos, tpos, chist);
  k_cellscan<<<1, 1024, 0, stream>>>(chist, crp);
  k_cellscatter<<<(2 * NA + 255) / 256, 256, 0, stream>>>(apos, tpos, crp, ccur, ps, pid);
  k_nbr2<<<(2 * NA + 255) / 256, 256, 0, stream>>>(apos, crp, ps, pid, a_idx, a_cnt, t_idx, t_cnt);

  // build x = [self | gat_a | gat_t]
  k_buildx<<<(NA + 255) / 256, 256, 0, stream>>>(own_obs, apos, tpos, W_self, b_self,
                                                 agWl, agWr, agatt, agb, tgWl, tgWr, tgatt, tgb,
                                                 a_idx, a_cnt, t_idx, t_cnt, x);

  // two graph-filter + BN + residual layers
  for (int l = 0; l < 2; ++l) {
    const ushort_t* Whl = Wh + (size_t)l * 65536;
    const ushort_t* Wll = Wlo + (size_t)l * 65536;
    const float* bl = gfb + (size_t)l * 128;
    const float* gl = bng + (size_t)l * 128;
    const float* bb = bnb + (size_t)l * 128;
    k_shift<<<NA / 4, 256, 0, stream>>>(x, sh1, rp, col);
    k_shift<<<NA / 4, 256, 0, stream>>>(sh1, sh2, rp, col);
    k_shift<<<NA / 4, 256, 0, stream>>>(sh2, sh3, rp, col);
    k_gemm_mfma3<<<NA / 16, 256, 0, stream>>>(x, sh1, sh2, sh3, Whl, Wll, bl, y);
    hipMemsetAsync(stats, 0, 256 * 8, stream);
    k_bnred<<<64, 256, 0, stream>>>(y, stats);
    k_bnfin<<<1, 128, 0, stream>>>(stats, gl, bb, AB);
    k_bnapply<<<(NA * 128) / 256, 256, 0, stream>>>(y, AB, x);
  }

  k_read<<<(NA + 255) / 256, 256, 0, stream>>>(x, Wread, bread, (float*)d_out);
}

// Round 5
// 394.377 us; speedup vs baseline: 1.6329x; 1.0026x over previous
//
#include <hip/hip_runtime.h>

typedef unsigned long long u64;
typedef unsigned int u32;
typedef unsigned short ushort_t;

#define NA 10000
#define NE 320000
#define KN 10
#define GRID 50
#define NCELL (GRID * GRID)      // 2500 cells of width 2.0 over [0,100)^2

typedef __attribute__((ext_vector_type(8))) short short8v;
typedef __attribute__((ext_vector_type(4))) float f32x4;

// ---------------- bf16 helpers (RNE) ----------------
__device__ __forceinline__ u32 f2bf(float f) {
  union { float f; u32 u; } v; v.f = f;
  return (v.u + 0x7fffu + ((v.u >> 16) & 1u)) >> 16;
}
__device__ __forceinline__ float bf2f(u32 b) {
  union { u32 u; float f; } v; v.u = b << 16;
  return v.f;
}

// ---------------- top-10 (d2,idx) maintenance ----------------
__device__ __forceinline__ void insert10(u64* top, u64 key) {
#pragma unroll
  for (int t = 9; t > 0; --t) {
    u64 prev = top[t - 1];
    u64 cur = top[t];
    top[t] = (key < prev) ? prev : ((key < cur) ? key : cur);
  }
  top[0] = (key < top[0]) ? key : top[0];
}

__device__ __forceinline__ int cell_of(float2 p) {
  int cx = (int)(p.x * 0.5f);            // exact: *0.5 is a pow2 multiply
  int cy = (int)(p.y * 0.5f);
  cx = min(max(cx, 0), GRID - 1);
  cy = min(max(cy, 0), GRID - 1);
  return cy * GRID + cx;
}

// ---------------- fused zero-init (replaces 4 memsets) ----------------
__global__ __launch_bounds__(256) void k_zero(int* __restrict__ deg, int* __restrict__ cur,
                                              int* __restrict__ chist, int* __restrict__ ccur) {
  int i = blockIdx.x * 256 + threadIdx.x;
  if (i < NA) deg[i] = 0;
  else if (i < 2 * NA) cur[i - NA] = 0;
  else if (i < 2 * NA + 2 * NCELL) chist[i - 2 * NA] = 0;
  else if (i < 2 * NA + 4 * NCELL) ccur[i - 2 * NA - 2 * NCELL] = 0;
}

// ---------------- fused histograms: edge degree + cell counts ----------------
__global__ __launch_bounds__(256) void k_hist_all(const int* __restrict__ edst,
                                                  const float2* __restrict__ apos,
                                                  const float2* __restrict__ tpos,
                                                  int* __restrict__ deg, int* __restrict__ chist) {
  int i = blockIdx.x * 256 + threadIdx.x;
  if (i < NE) {
    atomicAdd(&deg[edst[i]], 1);
  } else if (i < NE + 2 * NA) {
    int ii = i - NE;
    int graph = (ii >= NA) ? 1 : 0;
    int idx = ii - graph * NA;
    float2 p = graph ? tpos[idx] : apos[idx];
    atomicAdd(&chist[graph * NCELL + cell_of(p)], 1);
  }
}

// ---------------- fused scans: block 0 = edge CSR, block 1 = cell CSR ----------------
__global__ __launch_bounds__(1024) void k_scan_all(const int* __restrict__ deg, int* __restrict__ rp,
                                                   const int* __restrict__ chist, int* __restrict__ crp) {
  __shared__ int part[1024];
  int t = threadIdx.x;
  const int* in;
  int* out;
  int per, tot;
  if (blockIdx.x == 0) { in = deg; out = rp; per = 10; tot = NA; }
  else { in = chist; out = crp; per = 5; tot = 2 * NCELL; }
  int beg = min(t * per, tot), end = min(beg + per, tot);
  int s = 0;
  for (int i = beg; i < end; ++i) s += in[i];
  part[t] = s;
  __syncthreads();
  for (int o = 1; o < 1024; o <<= 1) {
    int v = part[t];
    int u = (t >= o) ? part[t - o] : 0;
    __syncthreads();
    part[t] = v + u;
    __syncthreads();
  }
  int base = (t > 0) ? part[t - 1] : 0;
  for (int i = beg; i < end; ++i) { out[i] = base; base += in[i]; }
  if (t == 1023) out[tot] = part[1023];
}

// ---------------- fused scatters: edges into CSR, points into cells ----------------
__global__ __launch_bounds__(256) void k_scatter_all(const int* __restrict__ esrc, const int* __restrict__ edst,
                                                     const int* __restrict__ rp, int* __restrict__ cur,
                                                     int* __restrict__ col,
                                                     const float2* __restrict__ apos, const float2* __restrict__ tpos,
                                                     const int* __restrict__ crp, int* __restrict__ ccur,
                                                     float2* __restrict__ ps, int* __restrict__ pid) {
  int i = blockIdx.x * 256 + threadIdx.x;
  if (i < NE) {
    int d = edst[i];
    int p = atomicAdd(&cur[d], 1);
    col[rp[d] + p] = esrc[i];
  } else if (i < NE + 2 * NA) {
    int ii = i - NE;
    int graph = (ii >= NA) ? 1 : 0;
    int idx = ii - graph * NA;
    float2 p = graph ? tpos[idx] : apos[idx];
    int gc = graph * NCELL + cell_of(p);
    int o = crp[gc] + atomicAdd(&ccur[gc], 1);
    ps[o] = p;
    pid[o] = idx;
  }
}

// ---------------- binned neighbor search: exact top-10 within radius ----------------
__global__ __launch_bounds__(256) void k_nbr2(const float2* __restrict__ apos,
                                              const int* __restrict__ rp,
                                              const float2* __restrict__ ps, const int* __restrict__ pid,
                                              int* __restrict__ a_idx, int* __restrict__ a_cnt,
                                              int* __restrict__ t_idx, int* __restrict__ t_cnt) {
  int tid = blockIdx.x * 256 + threadIdx.x;
  if (tid >= 2 * NA) return;
  int graph = (tid >= NA) ? 1 : 0;
  int q = tid - graph * NA;
  float2 qp = apos[q];
  int cx = min(max((int)(qp.x * 0.5f), 0), GRID - 1);
  int cy = min(max((int)(qp.y * 0.5f), 0), GRID - 1);

  u64 top[10];
#pragma unroll
  for (int t = 0; t < 10; ++t) top[t] = ~0ull;

  int x0 = max(cx - 1, 0), x1 = min(cx + 1, GRID - 1);
  int y0 = max(cy - 1, 0), y1 = min(cy + 1, GRID - 1);
  for (int yy = y0; yy <= y1; ++yy) {
    int cb = graph * NCELL + yy * GRID + x0;
    int ce = graph * NCELL + yy * GRID + x1;
    int b = rp[cb], e = rp[ce + 1];   // contiguous cells -> contiguous points
    for (int j = b; j < e; ++j) {
      float2 kp = ps[j];
      float dx = qp.x - kp.x;
      float dy = qp.y - kp.y;
      float d2 = __fadd_rn(__fmul_rn(dx, dx), __fmul_rn(dy, dy));
      int g = pid[j];
      if (d2 <= 4.0f && !(graph == 0 && g == q)) {
        u64 key = ((u64)__float_as_uint(d2) << 32) | (u32)g;
        if (key < top[9]) insert10(top, key);
      }
    }
  }
  int cnt = 0;
#pragma unroll
  for (int t = 0; t < 10; ++t) cnt += (top[t] != ~0ull) ? 1 : 0;
  int* oi = graph ? t_idx : a_idx;
#pragma unroll
  for (int t = 0; t < 10; ++t) oi[(size_t)q * 10 + t] = (int)(u32)(top[t] & 0xffffffffu);
  if (graph) t_cnt[q] = cnt; else a_cnt[q] = cnt;
}

// ---------------- GATv2 (32 channels, K<=10), fully unrolled ----------------
__device__ __forceinline__ void gat32(float qx, float qy,
                                      const float2* __restrict__ srcpos,
                                      const int* __restrict__ idxlist, int cnt,
                                      const float* __restrict__ Wl, const float* __restrict__ Wr,
                                      const float* __restrict__ att, const float* __restrict__ bb,
                                      float* __restrict__ out) {
  float xr[32];
#pragma unroll
  for (int c = 0; c < 32; ++c) xr[c] = qx * Wr[c] + qy * Wr[32 + c];
  float pjx[10], pjy[10], pv[10];
  float m = -1e30f;
#pragma unroll
  for (int k = 0; k < 10; ++k) {
    bool valid = (k < cnt);
    int j = valid ? idxlist[k] : 0;
    float2 p = srcpos[j];
    pjx[k] = p.x; pjy[k] = p.y;
    float sacc = 0.f;
#pragma unroll
    for (int c = 0; c < 32; ++c) {
      float xl = p.x * Wl[c] + p.y * Wl[32 + c];
      float g = xl + xr[c];
      g = (g >= 0.f) ? g : 0.2f * g;
      sacc += att[c] * g;
    }
    pv[k] = sacc;
    m = valid ? fmaxf(m, sacc) : m;
  }
  float sum = 0.f;
#pragma unroll
  for (int k = 0; k < 10; ++k) {
    float e = (k < cnt) ? expf(pv[k] - m) : 0.f;
    pv[k] = e;
    sum += e;
  }
  float inv = 1.f / (sum + 1e-16f);
#pragma unroll
  for (int c = 0; c < 32; ++c) out[c] = bb[c];
#pragma unroll
  for (int k = 0; k < 10; ++k) {
    float a = pv[k] * inv;
#pragma unroll
    for (int c = 0; c < 32; ++c) {
      float xl = pjx[k] * Wl[c] + pjy[k] * Wl[32 + c];
      out[c] += a * xl;
    }
  }
}

__global__ __launch_bounds__(256) void k_buildx(
    const float* __restrict__ own_obs, const float2* __restrict__ apos, const float2* __restrict__ tpos,
    const float* __restrict__ W_self, const float* __restrict__ b_self,
    const float* __restrict__ agWl, const float* __restrict__ agWr,
    const float* __restrict__ agatt, const float* __restrict__ agb,
    const float* __restrict__ tgWl, const float* __restrict__ tgWr,
    const float* __restrict__ tgatt, const float* __restrict__ tgb,
    const int* __restrict__ a_idx, const int* __restrict__ a_cnt,
    const int* __restrict__ t_idx, const int* __restrict__ t_cnt,
    float* __restrict__ x) {
  __shared__ float sW[512], sb[64];
  __shared__ float sagWl[64], sagWr[64], sagatt[32], sagb[32];
  __shared__ float stgWl[64], stgWr[64], stgatt[32], stgb[32];
  int t = threadIdx.x;
  for (int i = t; i < 512; i += 256) sW[i] = W_self[i];
  if (t < 64) { sb[t] = b_self[t]; sagWl[t] = agWl[t]; sagWr[t] = agWr[t]; stgWl[t] = tgWl[t]; stgWr[t] = tgWr[t]; }
  if (t < 32) { sagatt[t] = agatt[t]; sagb[t] = agb[t]; stgatt[t] = tgatt[t]; stgb[t] = tgb[t]; }
  __syncthreads();
  int q = blockIdx.x * 256 + t;
  if (q >= NA) return;

  const float4* op = (const float4*)(own_obs + (size_t)q * 8);
  float4 o0 = op[0], o1 = op[1];
  float obs[8] = {o0.x, o0.y, o0.z, o0.w, o1.x, o1.y, o1.z, o1.w};
  float* xrow = x + (size_t)q * 128;
#pragma unroll
  for (int c4 = 0; c4 < 16; ++c4) {
    float4 v;
    float* vp = (float*)&v;
#pragma unroll
    for (int jj = 0; jj < 4; ++jj) {
      int c = c4 * 4 + jj;
      float s = sb[c];
#pragma unroll
      for (int i = 0; i < 8; ++i) s += obs[i] * sW[i * 64 + c];
      vp[jj] = s;
    }
    *(float4*)(xrow + c4 * 4) = v;
  }

  float2 qp = apos[q];
  float outA[32];
  gat32(qp.x, qp.y, apos, a_idx + (size_t)q * 10, a_cnt[q], sagWl, sagWr, sagatt, sagb, outA);
#pragma unroll
  for (int c4 = 0; c4 < 8; ++c4)
    *(float4*)(xrow + 64 + c4 * 4) = make_float4(outA[c4 * 4], outA[c4 * 4 + 1], outA[c4 * 4 + 2], outA[c4 * 4 + 3]);

  float outT[32];
  gat32(qp.x, qp.y, tpos, t_idx + (size_t)q * 10, t_cnt[q], stgWl, stgWr, stgatt, stgb, outT);
#pragma unroll
  for (int c4 = 0; c4 < 8; ++c4)
    *(float4*)(xrow + 96 + c4 * 4) = make_float4(outT[c4 * 4], outT[c4 * 4 + 1], outT[c4 * 4 + 2], outT[c4 * 4 + 3]);
}

// ---------------- half-row adjacency shift: L2-resident gather (2.56 MB working set) ----------------
__global__ __launch_bounds__(256) void k_shift_half(const float* __restrict__ xin,
                                                    float* __restrict__ xout,
                                                    const int* __restrict__ rp,
                                                    const int* __restrict__ col,
                                                    int chbase) {
  int w = blockIdx.x * 4 + (threadIdx.x >> 6);
  int lane = threadIdx.x & 63;
  if (w >= NA) return;
  int beg = rp[w], end = rp[w + 1];
  const float* __restrict__ base = xin + chbase + lane;
  float acc = 0.f;
  int j = beg;
  for (; j + 3 < end; j += 4) {
    int s0 = col[j], s1 = col[j + 1], s2 = col[j + 2], s3 = col[j + 3];
    float v0 = base[(size_t)s0 * 128];
    float v1 = base[(size_t)s1 * 128];
    float v2 = base[(size_t)s2 * 128];
    float v3 = base[(size_t)s3 * 128];
    acc += (v0 + v1) + (v2 + v3);
  }
  for (; j < end; ++j) acc += base[(size_t)col[j] * 128];
  // nt store: keep the 2.5 MB output stream out of L2 so the gather operand stays resident
  __builtin_nontemporal_store(acc, xout + (size_t)w * 128 + chbase + lane);
}

// ---------------- W repack: f32 [l][t][k][n] -> bf16 hi/lo B-frag layout [l][t][kt][ct][lane][8] ----------------
__global__ __launch_bounds__(256) void k_packw(const float* __restrict__ gfW,
                                               ushort_t* __restrict__ Wh, ushort_t* __restrict__ Wlo) {
  int tid = blockIdx.x * 256 + threadIdx.x;   // 2*4*128*128 = 131072
  if (tid >= 131072) return;
  int l = tid >> 16;
  int rem = tid & 65535;
  int t = rem >> 14;
  int k = (rem >> 7) & 127;
  int n = rem & 127;
  float v = gfW[(size_t)tid];                 // gfW is [l][t][k][n] row-major contiguous
  int kt = k >> 5;
  int hi = (k >> 3) & 3;
  int j = k & 7;
  int ct = n >> 4;
  int lane = hi * 16 + (n & 15);
  size_t dst = (((((size_t)(l * 4 + t) * 4 + kt) * 8 + ct) * 64 + lane) * 8 + j);
  u32 h = f2bf(v);
  float r = v - bf2f(h);
  Wh[dst] = (ushort_t)h;
  Wlo[dst] = (ushort_t)f2bf(r);
}

// ---------------- MFMA 4-tap GEMM, bf16x3 split precision (f32 inputs, ~f32 accuracy) ----------------
__global__ __launch_bounds__(256) void k_gemm_mfma3(const float* __restrict__ a0, const float* __restrict__ a1,
                                                    const float* __restrict__ a2, const float* __restrict__ a3,
                                                    const ushort_t* __restrict__ Wh, const ushort_t* __restrict__ Wlo,
                                                    const float* __restrict__ b, float* __restrict__ y) {
  const int lane = threadIdx.x & 63;
  const int wave = threadIdx.x >> 6;          // 0..3
  const int ct0 = wave * 2;
  const int row = lane & 15;
  const int hi = lane >> 4;
  const int rb = blockIdx.x * 16;             // 625 blocks * 16 rows = 10000

  f32x4 acc[2];
#pragma unroll
  for (int c = 0; c < 2; ++c) {
    float bv = b[(ct0 + c) * 16 + row];       // D col = lane&15
    acc[c][0] = bv; acc[c][1] = bv; acc[c][2] = bv; acc[c][3] = bv;
  }

  const float* aps[4] = {a0, a1, a2, a3};
#pragma unroll
  for (int t = 0; t < 4; ++t) {
    const float* at = aps[t];
#pragma unroll
    for (int kt = 0; kt < 4; ++kt) {
      const float* ap = at + (size_t)(rb + row) * 128 + kt * 32 + hi * 8;
      float4 fa = *(const float4*)(ap);
      float4 fb = *(const float4*)(ap + 4);
      float av[8] = {fa.x, fa.y, fa.z, fa.w, fb.x, fb.y, fb.z, fb.w};
      short8v ah, al;
#pragma unroll
      for (int j = 0; j < 8; ++j) {
        u32 h = f2bf(av[j]);
        float r = av[j] - bf2f(h);
        ah[j] = (short)h;
        al[j] = (short)f2bf(r);
      }
#pragma unroll
      for (int c = 0; c < 2; ++c) {
        size_t widx = ((((size_t)t * 4 + kt) * 8 + (ct0 + c)) * 64 + lane) * 8;
        short8v bh = *(const short8v*)(Wh + widx);
        short8v bl = *(const short8v*)(Wlo + widx);
        acc[c] = __builtin_amdgcn_mfma_f32_16x16x32_bf16(ah, bh, acc[c], 0, 0, 0);
        acc[c] = __builtin_amdgcn_mfma_f32_16x16x32_bf16(al, bh, acc[c], 0, 0, 0);
        acc[c] = __builtin_amdgcn_mfma_f32_16x16x32_bf16(ah, bl, acc[c], 0, 0, 0);
      }
    }
  }

#pragma unroll
  for (int c = 0; c < 2; ++c) {
#pragma unroll
    for (int r = 0; r < 4; ++r) {
      int grow = rb + hi * 4 + r;             // D row = (lane>>4)*4 + reg
      y[(size_t)grow * 128 + (ct0 + c) * 16 + row] = acc[c][r];
    }
  }
}

// ---------------- BatchNorm: deterministic partials (no atomics, no memset) ----------------
__global__ __launch_bounds__(256) void k_bnred(const float* __restrict__ y, double* __restrict__ parts) {
  int c = threadIdx.x & 127;
  int slice = blockIdx.x * 2 + (threadIdx.x >> 7);
  double s = 0.0, ss = 0.0;
  for (int r = slice; r < NA; r += 128) {
    double v = (double)y[(size_t)r * 128 + c];
    s += v;
    ss += v * v;
  }
  parts[(size_t)blockIdx.x * 512 + threadIdx.x] = s;
  parts[(size_t)blockIdx.x * 512 + 256 + threadIdx.x] = ss;
}

__global__ void k_bnfin(const double* __restrict__ parts, const float* __restrict__ gamma,
                        const float* __restrict__ beta, float* __restrict__ AB) {
  int c = threadIdx.x;   // 0..127
  double s = 0.0, ss = 0.0;
  for (int b = 0; b < 64; ++b) {
    const double* p = parts + (size_t)b * 512;
    s += p[c] + p[c + 128];
    ss += p[256 + c] + p[256 + c + 128];
  }
  double mu = s / (double)NA;
  double var = ss / (double)NA - mu * mu;
  double rs = 1.0 / sqrt(var + 1e-5);
  float A = (float)rs * gamma[c];
  float B = beta[c] - (float)(mu * rs) * gamma[c];
  AB[c] = A;
  AB[128 + c] = B;
}

__global__ __launch_bounds__(256) void k_bnapply(const float* __restrict__ y, const float* __restrict__ AB,
                                                 float* __restrict__ x) {
  int i = blockIdx.x * 256 + threadIdx.x;
  int c = i & 127;
  float v = y[i] * AB[c] + AB[128 + c];
  v = (v >= 0.f) ? v : 0.01f * v;
  x[i] += v;
}

// ---------------- readout ----------------
__global__ __launch_bounds__(256) void k_read(const float* __restrict__ x, const float* __restrict__ Wr,
                                              const float* __restrict__ br, float* __restrict__ out) {
  int q = blockIdx.x * 256 + threadIdx.x;
  if (q >= NA) return;
  float a0 = br[0], a1 = br[1];
  const float* xr = x + (size_t)q * 128;
#pragma unroll 8
  for (int c = 0; c < 128; ++c) {
    float v = xr[c];
    a0 += v * Wr[c * 2 + 0];
    a1 += v * Wr[c * 2 + 1];
  }
  out[q * 2 + 0] = a0;
  out[q * 2 + 1] = a1;
}

extern "C" void kernel_launch(void* const* d_in, const int* in_sizes, int n_in,
                              void* d_out, int out_size, void* d_ws, size_t ws_size,
                              hipStream_t stream) {
  (void)in_sizes; (void)n_in; (void)out_size; (void)ws_size;
  const float* own_obs = (const float*)d_in[0];
  const float2* apos = (const float2*)d_in[1];
  const float2* tpos = (const float2*)d_in[2];
  const float* W_self = (const float*)d_in[3];
  const float* b_self = (const float*)d_in[4];
  const float* agWl = (const float*)d_in[5];
  const float* agWr = (const float*)d_in[6];
  const float* agatt = (const float*)d_in[7];
  const float* agb = (const float*)d_in[8];
  const float* tgWl = (const float*)d_in[9];
  const float* tgWr = (const float*)d_in[10];
  const float* tgatt = (const float*)d_in[11];
  const float* tgb = (const float*)d_in[12];
  const float* gfW = (const float*)d_in[13];
  const float* gfb = (const float*)d_in[14];
  const float* bng = (const float*)d_in[15];
  const float* bnb = (const float*)d_in[16];
  const float* Wread = (const float*)d_in[17];
  const float* bread = (const float*)d_in[18];
  const int* ei = (const int*)d_in[19];
  const int* esrc = ei;
  const int* edst = ei + NE;

  char* w = (char*)d_ws;
  size_t off = 0;
  auto take = [&](size_t bytes) -> void* {
    void* p = w + off;
    off += (bytes + 255) & ~(size_t)255;
    return p;
  };
  int* a_idx = (int*)take((size_t)NA * KN * 4);
  int* t_idx = (int*)take((size_t)NA * KN * 4);
  int* a_cnt = (int*)take((size_t)NA * 4);
  int* t_cnt = (int*)take((size_t)NA * 4);
  float* x = (float*)take((size_t)NA * 128 * 4);
  float* y = (float*)take((size_t)NA * 128 * 4);
  float* sh1 = (float*)take((size_t)NA * 128 * 4);
  float* sh2 = (float*)take((size_t)NA * 128 * 4);
  float* sh3 = (float*)take((size_t)NA * 128 * 4);
  ushort_t* Wh = (ushort_t*)take((size_t)131072 * 2);
  ushort_t* Wlo = (ushort_t*)take((size_t)131072 * 2);
  double* parts = (double*)take((size_t)64 * 512 * 8);
  float* AB = (float*)take(256 * 4);
  int* deg = (int*)take((size_t)NA * 4);
  int* cur = (int*)take((size_t)NA * 4);
  int* rp = (int*)take((size_t)(NA + 1) * 4);
  int* col = (int*)take((size_t)NE * 4);
  int* chist = (int*)take((size_t)2 * NCELL * 4);
  int* crp = (int*)take((size_t)(2 * NCELL + 1) * 4);
  int* ccur = (int*)take((size_t)2 * NCELL * 4);
  float2* ps = (float2*)take((size_t)2 * NA * 8);
  int* pid = (int*)take((size_t)2 * NA * 4);

  // zero counters, then fused CSR+cell builds
  k_zero<<<(2 * NA + 4 * NCELL + 255) / 256, 256, 0, stream>>>(deg, cur, chist, ccur);
  k_hist_all<<<(NE + 2 * NA + 255) / 256, 256, 0, stream>>>(edst, apos, tpos, deg, chist);
  k_scan_all<<<2, 1024, 0, stream>>>(deg, rp, chist, crp);
  k_scatter_all<<<(NE + 2 * NA + 255) / 256, 256, 0, stream>>>(esrc, edst, rp, cur, col,
                                                               apos, tpos, crp, ccur, ps, pid);

  // W repack to bf16 hi/lo B-frag layout
  k_packw<<<131072 / 256, 256, 0, stream>>>(gfW, Wh, Wlo);

  // binned neighbor search
  k_nbr2<<<(2 * NA + 255) / 256, 256, 0, stream>>>(apos, crp, ps, pid, a_idx, a_cnt, t_idx, t_cnt);

  // build x = [self | gat_a | gat_t]
  k_buildx<<<(NA + 255) / 256, 256, 0, stream>>>(own_obs, apos, tpos, W_self, b_self,
                                                 agWl, agWr, agatt, agb, tgWl, tgWr, tgatt, tgb,
                                                 a_idx, a_cnt, t_idx, t_cnt, x);

  // two graph-filter + BN + residual layers
  for (int l = 0; l < 2; ++l) {
    const ushort_t* Whl = Wh + (size_t)l * 65536;
    const ushort_t* Wll = Wlo + (size_t)l * 65536;
    const float* bl = gfb + (size_t)l * 128;
    const float* gl = bng + (size_t)l * 128;
    const float* bb = bnb + (size_t)l * 128;
    // each shift = two channel-half passes; each pass's gather operand (2.56 MB) is per-XCD-L2-resident
    k_shift_half<<<NA / 4, 256, 0, stream>>>(x, sh1, rp, col, 0);
    k_shift_half<<<NA / 4, 256, 0, stream>>>(x, sh1, rp, col, 64);
    k_shift_half<<<NA / 4, 256, 0, stream>>>(sh1, sh2, rp, col, 0);
    k_shift_half<<<NA / 4, 256, 0, stream>>>(sh1, sh2, rp, col, 64);
    k_shift_half<<<NA / 4, 256, 0, stream>>>(sh2, sh3, rp, col, 0);
    k_shift_half<<<NA / 4, 256, 0, stream>>>(sh2, sh3, rp, col, 64);
    k_gemm_mfma3<<<NA / 16, 256, 0, stream>>>(x, sh1, sh2, sh3, Whl, Wll, bl, y);
    k_bnred<<<64, 256, 0, stream>>>(y, parts);
    k_bnfin<<<1, 128, 0, stream>>>(parts, gl, bb, AB);
    k_bnapply<<<(NA * 128) / 256, 256, 0, stream>>>(y, AB, x);
  }

  k_read<<<(NA + 255) / 256, 256, 0, stream>>>(x, Wread, bread, (float*)d_out);
}

// Round 6
// 348.318 us; speedup vs baseline: 1.8489x; 1.1322x over previous
//
#include <hip/hip_runtime.h>

typedef unsigned long long u64;
typedef unsigned int u32;
typedef unsigned short ushort_t;

#define NA 10000
#define NE 320000
#define KN 10
#define GRID 50
#define NCELL (GRID * GRID)      // 2500 cells of width 2.0 over [0,100)^2

typedef __attribute__((ext_vector_type(8))) short short8v;
typedef __attribute__((ext_vector_type(4))) float f32x4;

// ---------------- bf16 helpers (RNE) ----------------
__device__ __forceinline__ u32 f2bf(float f) {
  union { float f; u32 u; } v; v.f = f;
  return (v.u + 0x7fffu + ((v.u >> 16) & 1u)) >> 16;
}
__device__ __forceinline__ float bf2f(u32 b) {
  union { u32 u; float f; } v; v.u = b << 16;
  return v.f;
}

// ---------------- top-10 (d2,idx) maintenance ----------------
__device__ __forceinline__ void insert10(u64* top, u64 key) {
#pragma unroll
  for (int t = 9; t > 0; --t) {
    u64 prev = top[t - 1];
    u64 cur = top[t];
    top[t] = (key < prev) ? prev : ((key < cur) ? key : cur);
  }
  top[0] = (key < top[0]) ? key : top[0];
}

__device__ __forceinline__ int cell_of(float2 p) {
  int cx = (int)(p.x * 0.5f);            // exact: *0.5 is a pow2 multiply
  int cy = (int)(p.y * 0.5f);
  cx = min(max(cx, 0), GRID - 1);
  cy = min(max(cy, 0), GRID - 1);
  return cy * GRID + cx;
}

// ---------------- fused zero-init ----------------
__global__ __launch_bounds__(256) void k_zero(int* __restrict__ deg, int* __restrict__ cur,
                                              int* __restrict__ chist, int* __restrict__ ccur) {
  int i = blockIdx.x * 256 + threadIdx.x;
  if (i < NA) deg[i] = 0;
  else if (i < 2 * NA) cur[i - NA] = 0;
  else if (i < 2 * NA + 2 * NCELL) chist[i - 2 * NA] = 0;
  else if (i < 2 * NA + 4 * NCELL) ccur[i - 2 * NA - 2 * NCELL] = 0;
}

// ---------------- fused histograms: edge degree + cell counts ----------------
__global__ __launch_bounds__(256) void k_hist_all(const int* __restrict__ edst,
                                                  const float2* __restrict__ apos,
                                                  const float2* __restrict__ tpos,
                                                  int* __restrict__ deg, int* __restrict__ chist) {
  int i = blockIdx.x * 256 + threadIdx.x;
  if (i < NE) {
    atomicAdd(&deg[edst[i]], 1);
  } else if (i < NE + 2 * NA) {
    int ii = i - NE;
    int graph = (ii >= NA) ? 1 : 0;
    int idx = ii - graph * NA;
    float2 p = graph ? tpos[idx] : apos[idx];
    atomicAdd(&chist[graph * NCELL + cell_of(p)], 1);
  }
}

// ---------------- fused scans: block 0 = edge CSR, block 1 = cell CSR ----------------
__global__ __launch_bounds__(1024) void k_scan_all(const int* __restrict__ deg, int* __restrict__ rp,
                                                   const int* __restrict__ chist, int* __restrict__ crp) {
  __shared__ int part[1024];
  int t = threadIdx.x;
  const int* in;
  int* out;
  int per, tot;
  if (blockIdx.x == 0) { in = deg; out = rp; per = 10; tot = NA; }
  else { in = chist; out = crp; per = 5; tot = 2 * NCELL; }
  int beg = min(t * per, tot), end = min(beg + per, tot);
  int s = 0;
  for (int i = beg; i < end; ++i) s += in[i];
  part[t] = s;
  __syncthreads();
  for (int o = 1; o < 1024; o <<= 1) {
    int v = part[t];
    int u = (t >= o) ? part[t - o] : 0;
    __syncthreads();
    part[t] = v + u;
    __syncthreads();
  }
  int base = (t > 0) ? part[t - 1] : 0;
  for (int i = beg; i < end; ++i) { out[i] = base; base += in[i]; }
  if (t == 1023) out[tot] = part[1023];
}

// ---------------- fused scatters: edges into CSR, points into cells ----------------
__global__ __launch_bounds__(256) void k_scatter_all(const int* __restrict__ esrc, const int* __restrict__ edst,
                                                     const int* __restrict__ rp, int* __restrict__ cur,
                                                     int* __restrict__ col,
                                                     const float2* __restrict__ apos, const float2* __restrict__ tpos,
                                                     const int* __restrict__ crp, int* __restrict__ ccur,
                                                     float2* __restrict__ ps, int* __restrict__ pid) {
  int i = blockIdx.x * 256 + threadIdx.x;
  if (i < NE) {
    int d = edst[i];
    int p = atomicAdd(&cur[d], 1);
    col[rp[d] + p] = esrc[i];
  } else if (i < NE + 2 * NA) {
    int ii = i - NE;
    int graph = (ii >= NA) ? 1 : 0;
    int idx = ii - graph * NA;
    float2 p = graph ? tpos[idx] : apos[idx];
    int gc = graph * NCELL + cell_of(p);
    int o = crp[gc] + atomicAdd(&ccur[gc], 1);
    ps[o] = p;
    pid[o] = idx;
  }
}

// ---------------- binned neighbor search: exact top-10 within radius ----------------
__global__ __launch_bounds__(256) void k_nbr2(const float2* __restrict__ apos,
                                              const int* __restrict__ rp,
                                              const float2* __restrict__ ps, const int* __restrict__ pid,
                                              int* __restrict__ a_idx, int* __restrict__ a_cnt,
                                              int* __restrict__ t_idx, int* __restrict__ t_cnt) {
  int tid = blockIdx.x * 256 + threadIdx.x;
  if (tid >= 2 * NA) return;
  int graph = (tid >= NA) ? 1 : 0;
  int q = tid - graph * NA;
  float2 qp = apos[q];
  int cx = min(max((int)(qp.x * 0.5f), 0), GRID - 1);
  int cy = min(max((int)(qp.y * 0.5f), 0), GRID - 1);

  u64 top[10];
#pragma unroll
  for (int t = 0; t < 10; ++t) top[t] = ~0ull;

  int x0 = max(cx - 1, 0), x1 = min(cx + 1, GRID - 1);
  int y0 = max(cy - 1, 0), y1 = min(cy + 1, GRID - 1);
  for (int yy = y0; yy <= y1; ++yy) {
    int cb = graph * NCELL + yy * GRID + x0;
    int ce = graph * NCELL + yy * GRID + x1;
    int b = rp[cb], e = rp[ce + 1];   // contiguous cells -> contiguous points
    for (int j = b; j < e; ++j) {
      float2 kp = ps[j];
      float dx = qp.x - kp.x;
      float dy = qp.y - kp.y;
      float d2 = __fadd_rn(__fmul_rn(dx, dx), __fmul_rn(dy, dy));
      int g = pid[j];
      if (d2 <= 4.0f && !(graph == 0 && g == q)) {
        u64 key = ((u64)__float_as_uint(d2) << 32) | (u32)g;
        if (key < top[9]) insert10(top, key);
      }
    }
  }
  int cnt = 0;
#pragma unroll
  for (int t = 0; t < 10; ++t) cnt += (top[t] != ~0ull) ? 1 : 0;
  int* oi = graph ? t_idx : a_idx;
#pragma unroll
  for (int t = 0; t < 10; ++t) oi[(size_t)q * 10 + t] = (int)(u32)(top[t] & 0xffffffffu);
  if (graph) t_cnt[q] = cnt; else a_cnt[q] = cnt;
}

// ---------------- self MLP: 8 threads/agent, 8 channels each ----------------
__global__ __launch_bounds__(64) void k_self(const float* __restrict__ own_obs,
                                             const float* __restrict__ W_self, const float* __restrict__ b_self,
                                             float* __restrict__ x) {
  __shared__ float sW[512], sb[64];
  int t = threadIdx.x;
  for (int i = t; i < 512; i += 64) sW[i] = W_self[i];
  sb[t] = b_self[t];
  __syncthreads();
  int gid = blockIdx.x * 64 + t;        // 80000 total
  int q = gid >> 3;
  int c8 = (gid & 7) * 8;
  if (q >= NA) return;
  const float4* op = (const float4*)(own_obs + (size_t)q * 8);
  float4 o0 = op[0], o1 = op[1];
  float obs[8] = {o0.x, o0.y, o0.z, o0.w, o1.x, o1.y, o1.z, o1.w};
  float out[8];
#pragma unroll
  for (int jj = 0; jj < 8; ++jj) {
    int c = c8 + jj;
    float s = sb[c];
#pragma unroll
    for (int i = 0; i < 8; ++i) s += obs[i] * sW[i * 64 + c];
    out[jj] = s;
  }
  float* xrow = x + (size_t)q * 128 + c8;
  *(float4*)(xrow) = make_float4(out[0], out[1], out[2], out[3]);
  *(float4*)(xrow + 4) = make_float4(out[4], out[5], out[6], out[7]);
}

// ---------------- GATv2 (32 ch, K<=10): 1 thread/agent, low reg pressure ----------------
__global__ __launch_bounds__(64) void k_gat(const float2* __restrict__ apos,
                                            const float2* __restrict__ srcpos,
                                            const int* __restrict__ idx_all, const int* __restrict__ cnt_all,
                                            const float* __restrict__ Wl, const float* __restrict__ Wr,
                                            const float* __restrict__ att, const float* __restrict__ bb,
                                            float* __restrict__ x, int outoff) {
  __shared__ float sWl[64], sWr[64], satt[32], sbb[32];
  int t = threadIdx.x;
  sWl[t] = Wl[t];
  sWr[t] = Wr[t];
  if (t < 32) { satt[t] = att[t]; sbb[t] = bb[t]; }
  __syncthreads();
  int q = blockIdx.x * 64 + t;
  if (q >= NA) return;
  float2 qp = apos[q];
  float xr[32];
#pragma unroll
  for (int c = 0; c < 32; ++c) xr[c] = qp.x * sWr[c] + qp.y * sWr[32 + c];
  const int* il = idx_all + (size_t)q * 10;
  int cnt = cnt_all[q];
  int idx[10];
#pragma unroll
  for (int k = 0; k < 10; ++k) idx[k] = (k < cnt) ? il[k] : 0;
  float pv[10];
  float m = -1e30f;
#pragma unroll
  for (int k = 0; k < 10; ++k) {
    float2 p = srcpos[idx[k]];
    float s = 0.f;
#pragma unroll
    for (int c = 0; c < 32; ++c) {
      float xl = p.x * sWl[c] + p.y * sWl[32 + c];
      float g = xl + xr[c];
      g = (g >= 0.f) ? g : 0.2f * g;
      s += satt[c] * g;
    }
    pv[k] = s;
    m = (k < cnt) ? fmaxf(m, s) : m;
  }
  float sum = 0.f;
#pragma unroll
  for (int k = 0; k < 10; ++k) {
    float e = (k < cnt) ? expf(pv[k] - m) : 0.f;
    pv[k] = e;
    sum += e;
  }
  float inv = 1.f / (sum + 1e-16f);
  float out[32];
#pragma unroll
  for (int c = 0; c < 32; ++c) out[c] = sbb[c];
#pragma unroll
  for (int k = 0; k < 10; ++k) {
    float a = pv[k] * inv;
    float2 p = srcpos[idx[k]];   // re-gather: 80 KB table is L1-hot
#pragma unroll
    for (int c = 0; c < 32; ++c) {
      float xl = p.x * sWl[c] + p.y * sWl[32 + c];
      out[c] += a * xl;
    }
  }
  float* xrow = x + (size_t)q * 128 + outoff;
#pragma unroll
  for (int c4 = 0; c4 < 8; ++c4)
    *(float4*)(xrow + c4 * 4) = make_float4(out[c4 * 4], out[c4 * 4 + 1], out[c4 * 4 + 2], out[c4 * 4 + 3]);
}

// ---------------- adjacency shift: 1 wave = 2 rows, full 512B row per gather instr ----------------
__global__ __launch_bounds__(256) void k_shift2(const float* __restrict__ xin, float* __restrict__ xout,
                                                const int* __restrict__ rp, const int* __restrict__ col) {
  int wid = threadIdx.x >> 6;           // wave in block: 0..3
  int lane = threadIdx.x & 63;
  int half = lane >> 5;                 // 0/1: which row of the pair
  int li = lane & 31;                   // lane within half: channel quad li*4..li*4+3
  int row = blockIdx.x * 8 + wid * 2 + half;   // grid 1250 * 8 = 10000
  int beg = rp[row], end = rp[row + 1];
  int deg = end - beg;
  int odeg = __shfl_xor(deg, 32);
  int maxdeg = max(deg, odeg);
  const f32x4* x4 = (const f32x4*)xin;
  f32x4 acc = {0.f, 0.f, 0.f, 0.f};
  for (int b = 0; b < maxdeg; b += 32) {
    int cv = (b + li < deg) ? col[beg + b + li] : 0;   // 32 cols per half, 1 instr
    int kmax = min(32, maxdeg - b);
    for (int k = 0; k < kmax; ++k) {
      int src = __builtin_amdgcn_ds_bpermute((half * 32 + k) << 2, cv);  // broadcast within half
      f32x4 v = x4[(size_t)src * 32 + li];              // 32 lanes x 16B = full row
      if (b + k < deg) acc += v;
    }
  }
  ((f32x4*)xout)[(size_t)row * 32 + li] = acc;
}

// ---------------- W repack: f32 [l][t][k][n] -> bf16 hi/lo B-frag layout ----------------
__global__ __launch_bounds__(256) void k_packw(const float* __restrict__ gfW,
                                               ushort_t* __restrict__ Wh, ushort_t* __restrict__ Wlo) {
  int tid = blockIdx.x * 256 + threadIdx.x;   // 2*4*128*128 = 131072
  if (tid >= 131072) return;
  int l = tid >> 16;
  int rem = tid & 65535;
  int t = rem >> 14;
  int k = (rem >> 7) & 127;
  int n = rem & 127;
  float v = gfW[(size_t)tid];
  int kt = k >> 5;
  int hi = (k >> 3) & 3;
  int j = k & 7;
  int ct = n >> 4;
  int lane = hi * 16 + (n & 15);
  size_t dst = (((((size_t)(l * 4 + t) * 4 + kt) * 8 + ct) * 64 + lane) * 8 + j);
  u32 h = f2bf(v);
  float r = v - bf2f(h);
  Wh[dst] = (ushort_t)h;
  Wlo[dst] = (ushort_t)f2bf(r);
}

// ---------------- MFMA 4-tap GEMM, bf16x3 split precision ----------------
__global__ __launch_bounds__(256) void k_gemm_mfma3(const float* __restrict__ a0, const float* __restrict__ a1,
                                                    const float* __restrict__ a2, const float* __restrict__ a3,
                                                    const ushort_t* __restrict__ Wh, const ushort_t* __restrict__ Wlo,
                                                    const float* __restrict__ b, float* __restrict__ y) {
  const int lane = threadIdx.x & 63;
  const int wave = threadIdx.x >> 6;          // 0..3
  const int ct0 = wave * 2;
  const int row = lane & 15;
  const int hi = lane >> 4;
  const int rb = blockIdx.x * 16;             // 625 blocks * 16 rows = 10000

  f32x4 acc[2];
#pragma unroll
  for (int c = 0; c < 2; ++c) {
    float bv = b[(ct0 + c) * 16 + row];
    acc[c][0] = bv; acc[c][1] = bv; acc[c][2] = bv; acc[c][3] = bv;
  }

  const float* aps[4] = {a0, a1, a2, a3};
#pragma unroll
  for (int t = 0; t < 4; ++t) {
    const float* at = aps[t];
#pragma unroll
    for (int kt = 0; kt < 4; ++kt) {
      const float* ap = at + (size_t)(rb + row) * 128 + kt * 32 + hi * 8;
      float4 fa = *(const float4*)(ap);
      float4 fb = *(const float4*)(ap + 4);
      float av[8] = {fa.x, fa.y, fa.z, fa.w, fb.x, fb.y, fb.z, fb.w};
      short8v ah, al;
#pragma unroll
      for (int j = 0; j < 8; ++j) {
        u32 h = f2bf(av[j]);
        float r = av[j] - bf2f(h);
        ah[j] = (short)h;
        al[j] = (short)f2bf(r);
      }
#pragma unroll
      for (int c = 0; c < 2; ++c) {
        size_t widx = ((((size_t)t * 4 + kt) * 8 + (ct0 + c)) * 64 + lane) * 8;
        short8v bh = *(const short8v*)(Wh + widx);
        short8v bl = *(const short8v*)(Wlo + widx);
        acc[c] = __builtin_amdgcn_mfma_f32_16x16x32_bf16(ah, bh, acc[c], 0, 0, 0);
        acc[c] = __builtin_amdgcn_mfma_f32_16x16x32_bf16(al, bh, acc[c], 0, 0, 0);
        acc[c] = __builtin_amdgcn_mfma_f32_16x16x32_bf16(ah, bl, acc[c], 0, 0, 0);
      }
    }
  }

#pragma unroll
  for (int c = 0; c < 2; ++c) {
#pragma unroll
    for (int r = 0; r < 4; ++r) {
      int grow = rb + hi * 4 + r;
      y[(size_t)grow * 128 + (ct0 + c) * 16 + row] = acc[c][r];
    }
  }
}

// ---------------- BatchNorm: deterministic partials ----------------
__global__ __launch_bounds__(256) void k_bnred(const float* __restrict__ y, double* __restrict__ parts) {
  int c = threadIdx.x & 127;
  int slice = blockIdx.x * 2 + (threadIdx.x >> 7);
  double s = 0.0, ss = 0.0;
  for (int r = slice; r < NA; r += 128) {
    double v = (double)y[(size_t)r * 128 + c];
    s += v;
    ss += v * v;
  }
  parts[(size_t)blockIdx.x * 512 + threadIdx.x] = s;
  parts[(size_t)blockIdx.x * 512 + 256 + threadIdx.x] = ss;
}

__global__ void k_bnfin(const double* __restrict__ parts, const float* __restrict__ gamma,
                        const float* __restrict__ beta, float* __restrict__ AB) {
  int c = threadIdx.x;   // 0..127
  double s = 0.0, ss = 0.0;
  for (int b = 0; b < 64; ++b) {
    const double* p = parts + (size_t)b * 512;
    s += p[c] + p[c + 128];
    ss += p[256 + c] + p[256 + c + 128];
  }
  double mu = s / (double)NA;
  double var = ss / (double)NA - mu * mu;
  double rs = 1.0 / sqrt(var + 1e-5);
  float A = (float)rs * gamma[c];
  float B = beta[c] - (float)(mu * rs) * gamma[c];
  AB[c] = A;
  AB[128 + c] = B;
}

__global__ __launch_bounds__(256) void k_bnapply(const float* __restrict__ y, const float* __restrict__ AB,
                                                 float* __restrict__ x) {
  int i = blockIdx.x * 256 + threadIdx.x;
  int c = i & 127;
  float v = y[i] * AB[c] + AB[128 + c];
  v = (v >= 0.f) ? v : 0.01f * v;
  x[i] += v;
}

// ---------------- readout ----------------
__global__ __launch_bounds__(256) void k_read(const float* __restrict__ x, const float* __restrict__ Wr,
                                              const float* __restrict__ br, float* __restrict__ out) {
  int q = blockIdx.x * 256 + threadIdx.x;
  if (q >= NA) return;
  float a0 = br[0], a1 = br[1];
  const float* xr = x + (size_t)q * 128;
#pragma unroll 8
  for (int c = 0; c < 128; ++c) {
    float v = xr[c];
    a0 += v * Wr[c * 2 + 0];
    a1 += v * Wr[c * 2 + 1];
  }
  out[q * 2 + 0] = a0;
  out[q * 2 + 1] = a1;
}

extern "C" void kernel_launch(void* const* d_in, const int* in_sizes, int n_in,
                              void* d_out, int out_size, void* d_ws, size_t ws_size,
                              hipStream_t stream) {
  (void)in_sizes; (void)n_in; (void)out_size; (void)ws_size;
  const float* own_obs = (const float*)d_in[0];
  const float2* apos = (const float2*)d_in[1];
  const float2* tpos = (const float2*)d_in[2];
  const float* W_self = (const float*)d_in[3];
  const float* b_self = (const float*)d_in[4];
  const float* agWl = (const float*)d_in[5];
  const float* agWr = (const float*)d_in[6];
  const float* agatt = (const float*)d_in[7];
  const float* agb = (const float*)d_in[8];
  const float* tgWl = (const float*)d_in[9];
  const float* tgWr = (const float*)d_in[10];
  const float* tgatt = (const float*)d_in[11];
  const float* tgb = (const float*)d_in[12];
  const float* gfW = (const float*)d_in[13];
  const float* gfb = (const float*)d_in[14];
  const float* bng = (const float*)d_in[15];
  const float* bnb = (const float*)d_in[16];
  const float* Wread = (const float*)d_in[17];
  const float* bread = (const float*)d_in[18];
  const int* ei = (const int*)d_in[19];
  const int* esrc = ei;
  const int* edst = ei + NE;

  char* w = (char*)d_ws;
  size_t off = 0;
  auto take = [&](size_t bytes) -> void* {
    void* p = w + off;
    off += (bytes + 255) & ~(size_t)255;
    return p;
  };
  int* a_idx = (int*)take((size_t)NA * KN * 4);
  int* t_idx = (int*)take((size_t)NA * KN * 4);
  int* a_cnt = (int*)take((size_t)NA * 4);
  int* t_cnt = (int*)take((size_t)NA * 4);
  float* x = (float*)take((size_t)NA * 128 * 4);
  float* y = (float*)take((size_t)NA * 128 * 4);
  float* sh1 = (float*)take((size_t)NA * 128 * 4);
  float* sh2 = (float*)take((size_t)NA * 128 * 4);
  float* sh3 = (float*)take((size_t)NA * 128 * 4);
  ushort_t* Wh = (ushort_t*)take((size_t)131072 * 2);
  ushort_t* Wlo = (ushort_t*)take((size_t)131072 * 2);
  double* parts = (double*)take((size_t)64 * 512 * 8);
  float* AB = (float*)take(256 * 4);
  int* deg = (int*)take((size_t)NA * 4);
  int* cur = (int*)take((size_t)NA * 4);
  int* rp = (int*)take((size_t)(NA + 1) * 4);
  int* col = (int*)take((size_t)NE * 4);
  int* chist = (int*)take((size_t)2 * NCELL * 4);
  int* crp = (int*)take((size_t)(2 * NCELL + 1) * 4);
  int* ccur = (int*)take((size_t)2 * NCELL * 4);
  float2* ps = (float2*)take((size_t)2 * NA * 8);
  int* pid = (int*)take((size_t)2 * NA * 4);

  // zero counters, then fused CSR+cell builds
  k_zero<<<(2 * NA + 4 * NCELL + 255) / 256, 256, 0, stream>>>(deg, cur, chist, ccur);
  k_hist_all<<<(NE + 2 * NA + 255) / 256, 256, 0, stream>>>(edst, apos, tpos, deg, chist);
  k_scan_all<<<2, 1024, 0, stream>>>(deg, rp, chist, crp);
  k_scatter_all<<<(NE + 2 * NA + 255) / 256, 256, 0, stream>>>(esrc, edst, rp, cur, col,
                                                               apos, tpos, crp, ccur, ps, pid);

  // W repack to bf16 hi/lo B-frag layout
  k_packw<<<131072 / 256, 256, 0, stream>>>(gfW, Wh, Wlo);

  // binned neighbor search
  k_nbr2<<<(2 * NA + 255) / 256, 256, 0, stream>>>(apos, crp, ps, pid, a_idx, a_cnt, t_idx, t_cnt);

  // build x = [self | gat_a | gat_t]
  k_self<<<(NA * 8 + 63) / 64, 64, 0, stream>>>(own_obs, W_self, b_self, x);
  k_gat<<<(NA + 63) / 64, 64, 0, stream>>>(apos, apos, a_idx, a_cnt, agWl, agWr, agatt, agb, x, 64);
  k_gat<<<(NA + 63) / 64, 64, 0, stream>>>(apos, tpos, t_idx, t_cnt, tgWl, tgWr, tgatt, tgb, x, 96);

  // two graph-filter + BN + residual layers
  for (int l = 0; l < 2; ++l) {
    const ushort_t* Whl = Wh + (size_t)l * 65536;
    const ushort_t* Wll = Wlo + (size_t)l * 65536;
    const float* bl = gfb + (size_t)l * 128;
    const float* gl = bng + (size_t)l * 128;
    const float* bb = bnb + (size_t)l * 128;
    k_shift2<<<NA / 8, 256, 0, stream>>>(x, sh1, rp, col);
    k_shift2<<<NA / 8, 256, 0, stream>>>(sh1, sh2, rp, col);
    k_shift2<<<NA / 8, 256, 0, stream>>>(sh2, sh3, rp, col);
    k_gemm_mfma3<<<NA / 16, 256, 0, stream>>>(x, sh1, sh2, sh3, Whl, Wll, bl, y);
    k_bnred<<<64, 256, 0, stream>>>(y, parts);
    k_bnfin<<<1, 128, 0, stream>>>(parts, gl, bb, AB);
    k_bnapply<<<(NA * 128) / 256, 256, 0, stream>>>(y, AB, x);
  }

  k_read<<<(NA + 255) / 256, 256, 0, stream>>>(x, Wread, bread, (float*)d_out);
}

// Round 7
// 289.641 us; speedup vs baseline: 2.2234x; 1.2026x over previous
//
#include <hip/hip_runtime.h>

typedef unsigned long long u64;
typedef unsigned int u32;
typedef unsigned short ushort_t;

#define NA 10000
#define NE 320000
#define KN 10
#define GRID 50
#define NCELL (GRID * GRID)      // 2500 cells of width 2.0 over [0,100)^2
#define GATB 157                 // ceil(NA/64)

typedef __attribute__((ext_vector_type(8))) short short8v;
typedef __attribute__((ext_vector_type(4))) float f32x4;

// ---------------- bf16 helpers (RNE) ----------------
__device__ __forceinline__ u32 f2bf(float f) {
  union { float f; u32 u; } v; v.f = f;
  return (v.u + 0x7fffu + ((v.u >> 16) & 1u)) >> 16;
}
__device__ __forceinline__ float bf2f(u32 b) {
  union { u32 u; float f; } v; v.u = b << 16;
  return v.f;
}

// ---------------- top-10 (d2,idx) maintenance ----------------
__device__ __forceinline__ void insert10(u64* top, u64 key) {
#pragma unroll
  for (int t = 9; t > 0; --t) {
    u64 prev = top[t - 1];
    u64 cur = top[t];
    top[t] = (key < prev) ? prev : ((key < cur) ? key : cur);
  }
  top[0] = (key < top[0]) ? key : top[0];
}

__device__ __forceinline__ int cell_of(float2 p) {
  int cx = (int)(p.x * 0.5f);            // exact: *0.5 is a pow2 multiply
  int cy = (int)(p.y * 0.5f);
  cx = min(max(cx, 0), GRID - 1);
  cy = min(max(cy, 0), GRID - 1);
  return cy * GRID + cx;
}

// ---------------- fused: zero counters + W repack (independent ranges) ----------------
__global__ __launch_bounds__(256) void k_zero_packw(int* __restrict__ deg, int* __restrict__ cur,
                                                    int* __restrict__ chist, int* __restrict__ ccur,
                                                    const float* __restrict__ gfW,
                                                    ushort_t* __restrict__ Wh, ushort_t* __restrict__ Wlo) {
  int i = blockIdx.x * 256 + threadIdx.x;
  if (i < NA) deg[i] = 0;
  else if (i < 2 * NA) cur[i - NA] = 0;
  else if (i < 2 * NA + 2 * NCELL) chist[i - 2 * NA] = 0;
  else if (i < 2 * NA + 4 * NCELL) ccur[i - 2 * NA - 2 * NCELL] = 0;
  if (i < 131072) {   // W repack: f32 [l][t][k][n] -> bf16 hi/lo B-frag layout
    int l = i >> 16;
    int rem = i & 65535;
    int t = rem >> 14;
    int k = (rem >> 7) & 127;
    int n = rem & 127;
    float v = gfW[(size_t)i];
    int kt = k >> 5;
    int hi = (k >> 3) & 3;
    int j = k & 7;
    int ct = n >> 4;
    int lane = hi * 16 + (n & 15);
    size_t dst = (((((size_t)(l * 4 + t) * 4 + kt) * 8 + ct) * 64 + lane) * 8 + j);
    u32 h = f2bf(v);
    float r = v - bf2f(h);
    Wh[dst] = (ushort_t)h;
    Wlo[dst] = (ushort_t)f2bf(r);
  }
}

// ---------------- fused: edge-degree hist + cell hist + self MLP ----------------
__global__ __launch_bounds__(256) void k_hist_self(const int* __restrict__ edst,
                                                   const float2* __restrict__ apos,
                                                   const float2* __restrict__ tpos,
                                                   int* __restrict__ deg, int* __restrict__ chist,
                                                   const float* __restrict__ own_obs,
                                                   const float* __restrict__ W_self, const float* __restrict__ b_self,
                                                   float* __restrict__ x) {
  __shared__ float sW[512], sb[64];
  int t = threadIdx.x;
  for (int i = t; i < 512; i += 256) sW[i] = W_self[i];
  if (t < 64) sb[t] = b_self[t];
  __syncthreads();
  int i = blockIdx.x * 256 + t;
  if (i < NE) {
    atomicAdd(&deg[edst[i]], 1);
  } else if (i < NE + 2 * NA) {
    int ii = i - NE;
    int graph = (ii >= NA) ? 1 : 0;
    int idx = ii - graph * NA;
    float2 p = graph ? tpos[idx] : apos[idx];
    atomicAdd(&chist[graph * NCELL + cell_of(p)], 1);
  } else if (i < NE + 2 * NA + 8 * NA) {
    int gid = i - NE - 2 * NA;
    int q = gid >> 3;
    int c8 = (gid & 7) * 8;
    const float4* op = (const float4*)(own_obs + (size_t)q * 8);
    float4 o0 = op[0], o1 = op[1];
    float obs[8] = {o0.x, o0.y, o0.z, o0.w, o1.x, o1.y, o1.z, o1.w};
    float out[8];
#pragma unroll
    for (int jj = 0; jj < 8; ++jj) {
      int c = c8 + jj;
      float s = sb[c];
#pragma unroll
      for (int k = 0; k < 8; ++k) s += obs[k] * sW[k * 64 + c];
      out[jj] = s;
    }
    float* xrow = x + (size_t)q * 128 + c8;
    *(float4*)(xrow) = make_float4(out[0], out[1], out[2], out[3]);
    *(float4*)(xrow + 4) = make_float4(out[4], out[5], out[6], out[7]);
  }
}

// ---------------- fused scans: block 0 = edge CSR, block 1 = cell CSR ----------------
__global__ __launch_bounds__(1024) void k_scan_all(const int* __restrict__ deg, int* __restrict__ rp,
                                                   const int* __restrict__ chist, int* __restrict__ crp) {
  __shared__ int part[1024];
  int t = threadIdx.x;
  const int* in;
  int* out;
  int per, tot;
  if (blockIdx.x == 0) { in = deg; out = rp; per = 10; tot = NA; }
  else { in = chist; out = crp; per = 5; tot = 2 * NCELL; }
  int beg = min(t * per, tot), end = min(beg + per, tot);
  int s = 0;
  for (int i = beg; i < end; ++i) s += in[i];
  part[t] = s;
  __syncthreads();
  for (int o = 1; o < 1024; o <<= 1) {
    int v = part[t];
    int u = (t >= o) ? part[t - o] : 0;
    __syncthreads();
    part[t] = v + u;
    __syncthreads();
  }
  int base = (t > 0) ? part[t - 1] : 0;
  for (int i = beg; i < end; ++i) { out[i] = base; base += in[i]; }
  if (t == 1023) out[tot] = part[1023];
}

// ---------------- fused scatters: edges into CSR, points into cells ----------------
__global__ __launch_bounds__(256) void k_scatter_all(const int* __restrict__ esrc, const int* __restrict__ edst,
                                                     const int* __restrict__ rp, int* __restrict__ cur,
                                                     int* __restrict__ col,
                                                     const float2* __restrict__ apos, const float2* __restrict__ tpos,
                                                     const int* __restrict__ crp, int* __restrict__ ccur,
                                                     float2* __restrict__ ps, int* __restrict__ pid) {
  int i = blockIdx.x * 256 + threadIdx.x;
  if (i < NE) {
    int d = edst[i];
    int p = atomicAdd(&cur[d], 1);
    col[rp[d] + p] = esrc[i];
  } else if (i < NE + 2 * NA) {
    int ii = i - NE;
    int graph = (ii >= NA) ? 1 : 0;
    int idx = ii - graph * NA;
    float2 p = graph ? tpos[idx] : apos[idx];
    int gc = graph * NCELL + cell_of(p);
    int o = crp[gc] + atomicAdd(&ccur[gc], 1);
    ps[o] = p;
    pid[o] = idx;
  }
}

// ---------------- binned neighbor search: exact top-10 within radius ----------------
__global__ __launch_bounds__(256) void k_nbr2(const float2* __restrict__ apos,
                                              const int* __restrict__ rp,
                                              const float2* __restrict__ ps, const int* __restrict__ pid,
                                              int* __restrict__ a_idx, int* __restrict__ a_cnt,
                                              int* __restrict__ t_idx, int* __restrict__ t_cnt) {
  int tid = blockIdx.x * 256 + threadIdx.x;
  if (tid >= 2 * NA) return;
  int graph = (tid >= NA) ? 1 : 0;
  int q = tid - graph * NA;
  float2 qp = apos[q];
  int cx = min(max((int)(qp.x * 0.5f), 0), GRID - 1);
  int cy = min(max((int)(qp.y * 0.5f), 0), GRID - 1);

  u64 top[10];
#pragma unroll
  for (int t = 0; t < 10; ++t) top[t] = ~0ull;

  int x0 = max(cx - 1, 0), x1 = min(cx + 1, GRID - 1);
  int y0 = max(cy - 1, 0), y1 = min(cy + 1, GRID - 1);
  for (int yy = y0; yy <= y1; ++yy) {
    int cb = graph * NCELL + yy * GRID + x0;
    int ce = graph * NCELL + yy * GRID + x1;
    int b = rp[cb], e = rp[ce + 1];   // contiguous cells -> contiguous points
    for (int j = b; j < e; ++j) {
      float2 kp = ps[j];
      float dx = qp.x - kp.x;
      float dy = qp.y - kp.y;
      float d2 = __fadd_rn(__fmul_rn(dx, dx), __fmul_rn(dy, dy));
      int g = pid[j];
      if (d2 <= 4.0f && !(graph == 0 && g == q)) {
        u64 key = ((u64)__float_as_uint(d2) << 32) | (u32)g;
        if (key < top[9]) insert10(top, key);
      }
    }
  }
  int cnt = 0;
#pragma unroll
  for (int t = 0; t < 10; ++t) cnt += (top[t] != ~0ull) ? 1 : 0;
  int* oi = graph ? t_idx : a_idx;
#pragma unroll
  for (int t = 0; t < 10; ++t) oi[(size_t)q * 10 + t] = (int)(u32)(top[t] & 0xffffffffu);
  if (graph) t_cnt[q] = cnt; else a_cnt[q] = cnt;
}

// ---------------- both GATs in one launch (blocks [0,157)=agent, [157,314)=target) ----------------
__global__ __launch_bounds__(64) void k_gat2(const float2* __restrict__ apos, const float2* __restrict__ tpos,
                                             const int* __restrict__ a_idx, const int* __restrict__ a_cnt,
                                             const int* __restrict__ t_idx, const int* __restrict__ t_cnt,
                                             const float* __restrict__ agWl, const float* __restrict__ agWr,
                                             const float* __restrict__ agatt, const float* __restrict__ agb,
                                             const float* __restrict__ tgWl, const float* __restrict__ tgWr,
                                             const float* __restrict__ tgatt, const float* __restrict__ tgb,
                                             float* __restrict__ x) {
  int graph = (blockIdx.x >= GATB) ? 1 : 0;
  int b0 = blockIdx.x - graph * GATB;
  const float2* srcpos = graph ? tpos : apos;
  const int* idx_all = graph ? t_idx : a_idx;
  const int* cnt_all = graph ? t_cnt : a_cnt;
  const float* Wl = graph ? tgWl : agWl;
  const float* Wr = graph ? tgWr : agWr;
  const float* att = graph ? tgatt : agatt;
  const float* bbp = graph ? tgb : agb;
  int outoff = graph ? 96 : 64;

  __shared__ float sWl[64], sWr[64], satt[32], sbb[32];
  int t = threadIdx.x;
  sWl[t] = Wl[t];
  sWr[t] = Wr[t];
  if (t < 32) { satt[t] = att[t]; sbb[t] = bbp[t]; }
  __syncthreads();
  int q = b0 * 64 + t;
  if (q >= NA) return;
  float2 qp = apos[q];
  float xr[32];
#pragma unroll
  for (int c = 0; c < 32; ++c) xr[c] = qp.x * sWr[c] + qp.y * sWr[32 + c];
  const int* il = idx_all + (size_t)q * 10;
  int cnt = cnt_all[q];
  int idx[10];
#pragma unroll
  for (int k = 0; k < 10; ++k) idx[k] = (k < cnt) ? il[k] : 0;
  float pv[10];
  float m = -1e30f;
#pragma unroll
  for (int k = 0; k < 10; ++k) {
    float2 p = srcpos[idx[k]];
    float s = 0.f;
#pragma unroll
    for (int c = 0; c < 32; ++c) {
      float xl = p.x * sWl[c] + p.y * sWl[32 + c];
      float g = xl + xr[c];
      g = (g >= 0.f) ? g : 0.2f * g;
      s += satt[c] * g;
    }
    pv[k] = s;
    m = (k < cnt) ? fmaxf(m, s) : m;
  }
  float sum = 0.f;
#pragma unroll
  for (int k = 0; k < 10; ++k) {
    float e = (k < cnt) ? expf(pv[k] - m) : 0.f;
    pv[k] = e;
    sum += e;
  }
  float inv = 1.f / (sum + 1e-16f);
  float out[32];
#pragma unroll
  for (int c = 0; c < 32; ++c) out[c] = sbb[c];
#pragma unroll
  for (int k = 0; k < 10; ++k) {
    float a = pv[k] * inv;
    float2 p = srcpos[idx[k]];   // re-gather: tables are L1/L2-hot
#pragma unroll
    for (int c = 0; c < 32; ++c) {
      float xl = p.x * sWl[c] + p.y * sWl[32 + c];
      out[c] += a * xl;
    }
  }
  float* xrow = x + (size_t)q * 128 + outoff;
#pragma unroll
  for (int c4 = 0; c4 < 8; ++c4)
    *(float4*)(xrow + c4 * 4) = make_float4(out[c4 * 4], out[c4 * 4 + 1], out[c4 * 4 + 2], out[c4 * 4 + 3]);
}

// ---------------- adjacency shift, XCD-partitioned channel halves ----------------
// half = (bid&7)>>2: XCDs 0-3 gather channels 0-63, XCDs 4-7 channels 64-127.
// Each XCD's 4MiB L2 then only caches a 2.56MB operand half -> L2-resident gathers.
__global__ __launch_bounds__(256) void k_shift3(const float* __restrict__ xin, float* __restrict__ xout,
                                                const int* __restrict__ rp, const int* __restrict__ col) {
  int bid = blockIdx.x;                       // grid 1256
  int half = (bid & 7) >> 2;
  int slot = (bid >> 3) * 4 + (bid & 3);      // 0..627
  if (slot >= 625) return;
  int wid = threadIdx.x >> 6;
  int lane = threadIdx.x & 63;
  int q = lane >> 4;                          // quarter-wave owns one row
  int li = lane & 15;                         // 16 lanes x f32x4 = 64 channels
  int row = slot * 16 + wid * 4 + q;
  int beg = rp[row], end = rp[row + 1];
  const f32x4* x4 = (const f32x4*)xin;
  int base = half * 16 + li;
  f32x4 acc = {0.f, 0.f, 0.f, 0.f};
  int j = beg;
  for (; j + 1 < end; j += 2) {
    int s0 = col[j], s1 = col[j + 1];         // uniform in quarter -> broadcast
    f32x4 v0 = x4[(size_t)s0 * 32 + base];
    f32x4 v1 = x4[(size_t)s1 * 32 + base];
    acc += v0;
    acc += v1;
  }
  if (j < end) acc += x4[(size_t)col[j] * 32 + base];
  ((f32x4*)xout)[(size_t)row * 32 + base] = acc;
}

// ---------------- MFMA 4-tap GEMM, bf16x3 split precision ----------------
__global__ __launch_bounds__(256) void k_gemm_mfma3(const float* __restrict__ a0, const float* __restrict__ a1,
                                                    const float* __restrict__ a2, const float* __restrict__ a3,
                                                    const ushort_t* __restrict__ Wh, const ushort_t* __restrict__ Wlo,
                                                    const float* __restrict__ b, float* __restrict__ y) {
  const int lane = threadIdx.x & 63;
  const int wave = threadIdx.x >> 6;          // 0..3
  const int ct0 = wave * 2;
  const int row = lane & 15;
  const int hi = lane >> 4;
  const int rb = blockIdx.x * 16;             // 625 blocks * 16 rows = 10000

  f32x4 acc[2];
#pragma unroll
  for (int c = 0; c < 2; ++c) {
    float bv = b[(ct0 + c) * 16 + row];
    acc[c][0] = bv; acc[c][1] = bv; acc[c][2] = bv; acc[c][3] = bv;
  }

  const float* aps[4] = {a0, a1, a2, a3};
#pragma unroll
  for (int t = 0; t < 4; ++t) {
    const float* at = aps[t];
#pragma unroll
    for (int kt = 0; kt < 4; ++kt) {
      const float* ap = at + (size_t)(rb + row) * 128 + kt * 32 + hi * 8;
      float4 fa = *(const float4*)(ap);
      float4 fb = *(const float4*)(ap + 4);
      float av[8] = {fa.x, fa.y, fa.z, fa.w, fb.x, fb.y, fb.z, fb.w};
      short8v ah, al;
#pragma unroll
      for (int j = 0; j < 8; ++j) {
        u32 h = f2bf(av[j]);
        float r = av[j] - bf2f(h);
        ah[j] = (short)h;
        al[j] = (short)f2bf(r);
      }
#pragma unroll
      for (int c = 0; c < 2; ++c) {
        size_t widx = ((((size_t)t * 4 + kt) * 8 + (ct0 + c)) * 64 + lane) * 8;
        short8v bh = *(const short8v*)(Wh + widx);
        short8v bl = *(const short8v*)(Wlo + widx);
        acc[c] = __builtin_amdgcn_mfma_f32_16x16x32_bf16(ah, bh, acc[c], 0, 0, 0);
        acc[c] = __builtin_amdgcn_mfma_f32_16x16x32_bf16(al, bh, acc[c], 0, 0, 0);
        acc[c] = __builtin_amdgcn_mfma_f32_16x16x32_bf16(ah, bl, acc[c], 0, 0, 0);
      }
    }
  }

#pragma unroll
  for (int c = 0; c < 2; ++c) {
#pragma unroll
    for (int r = 0; r < 4; ++r) {
      int grow = rb + hi * 4 + r;
      y[(size_t)grow * 128 + (ct0 + c) * 16 + row] = acc[c][r];
    }
  }
}

// ---------------- BatchNorm: deterministic partials (128 blocks) ----------------
__global__ __launch_bounds__(256) void k_bnred(const float* __restrict__ y, double* __restrict__ parts) {
  int c = threadIdx.x & 127;
  int slice = blockIdx.x * 2 + (threadIdx.x >> 7);   // 256 slices
  double s = 0.0, ss = 0.0;
  for (int r = slice; r < NA; r += 256) {
    double v = (double)y[(size_t)r * 128 + c];
    s += v;
    ss += v * v;
  }
  parts[(size_t)blockIdx.x * 512 + threadIdx.x] = s;
  parts[(size_t)blockIdx.x * 512 + 256 + threadIdx.x] = ss;
}

// finalize AB per-block (redundant but cheap), then grid-stride apply + residual
__global__ __launch_bounds__(256) void k_bnapply_f(const float* __restrict__ y, const double* __restrict__ parts,
                                                   const float* __restrict__ gamma, const float* __restrict__ beta,
                                                   float* __restrict__ x) {
  __shared__ float sAB[256];
  int t = threadIdx.x;
  if (t < 128) {
    double s = 0.0, ss = 0.0;
    for (int b = 0; b < 128; ++b) {
      const double* p = parts + (size_t)b * 512;
      s += p[t] + p[t + 128];
      ss += p[256 + t] + p[256 + t + 128];
    }
    double mu = s / (double)NA;
    double var = ss / (double)NA - mu * mu;
    double rs = 1.0 / sqrt(var + 1e-5);
    sAB[t] = (float)rs * gamma[t];
    sAB[128 + t] = beta[t] - (float)(mu * rs) * gamma[t];
  }
  __syncthreads();
  const int n4 = NA * 32;
  for (int i = blockIdx.x * 256 + t; i < n4; i += gridDim.x * 256) {
    float4 yv = ((const float4*)y)[i];
    int c = (i & 31) * 4;
    float v0 = yv.x * sAB[c + 0] + sAB[128 + c + 0];
    float v1 = yv.y * sAB[c + 1] + sAB[128 + c + 1];
    float v2 = yv.z * sAB[c + 2] + sAB[128 + c + 2];
    float v3 = yv.w * sAB[c + 3] + sAB[128 + c + 3];
    v0 = (v0 >= 0.f) ? v0 : 0.01f * v0;
    v1 = (v1 >= 0.f) ? v1 : 0.01f * v1;
    v2 = (v2 >= 0.f) ? v2 : 0.01f * v2;
    v3 = (v3 >= 0.f) ? v3 : 0.01f * v3;
    float4 xv = ((float4*)x)[i];
    xv.x += v0; xv.y += v1; xv.z += v2; xv.w += v3;
    ((float4*)x)[i] = xv;
  }
}

// ---------------- readout ----------------
__global__ __launch_bounds__(256) void k_read(const float* __restrict__ x, const float* __restrict__ Wr,
                                              const float* __restrict__ br, float* __restrict__ out) {
  int q = blockIdx.x * 256 + threadIdx.x;
  if (q >= NA) return;
  float a0 = br[0], a1 = br[1];
  const float* xr = x + (size_t)q * 128;
#pragma unroll 8
  for (int c = 0; c < 128; ++c) {
    float v = xr[c];
    a0 += v * Wr[c * 2 + 0];
    a1 += v * Wr[c * 2 + 1];
  }
  out[q * 2 + 0] = a0;
  out[q * 2 + 1] = a1;
}

extern "C" void kernel_launch(void* const* d_in, const int* in_sizes, int n_in,
                              void* d_out, int out_size, void* d_ws, size_t ws_size,
                              hipStream_t stream) {
  (void)in_sizes; (void)n_in; (void)out_size; (void)ws_size;
  const float* own_obs = (const float*)d_in[0];
  const float2* apos = (const float2*)d_in[1];
  const float2* tpos = (const float2*)d_in[2];
  const float* W_self = (const float*)d_in[3];
  const float* b_self = (const float*)d_in[4];
  const float* agWl = (const float*)d_in[5];
  const float* agWr = (const float*)d_in[6];
  const float* agatt = (const float*)d_in[7];
  const float* agb = (const float*)d_in[8];
  const float* tgWl = (const float*)d_in[9];
  const float* tgWr = (const float*)d_in[10];
  const float* tgatt = (const float*)d_in[11];
  const float* tgb = (const float*)d_in[12];
  const float* gfW = (const float*)d_in[13];
  const float* gfb = (const float*)d_in[14];
  const float* bng = (const float*)d_in[15];
  const float* bnb = (const float*)d_in[16];
  const float* Wread = (const float*)d_in[17];
  const float* bread = (const float*)d_in[18];
  const int* ei = (const int*)d_in[19];
  const int* esrc = ei;
  const int* edst = ei + NE;

  char* w = (char*)d_ws;
  size_t off = 0;
  auto take = [&](size_t bytes) -> void* {
    void* p = w + off;
    off += (bytes + 255) & ~(size_t)255;
    return p;
  };
  int* a_idx = (int*)take((size_t)NA * KN * 4);
  int* t_idx = (int*)take((size_t)NA * KN * 4);
  int* a_cnt = (int*)take((size_t)NA * 4);
  int* t_cnt = (int*)take((size_t)NA * 4);
  float* x = (float*)take((size_t)NA * 128 * 4);
  float* y = (float*)take((size_t)NA * 128 * 4);
  float* sh1 = (float*)take((size_t)NA * 128 * 4);
  float* sh2 = (float*)take((size_t)NA * 128 * 4);
  float* sh3 = (float*)take((size_t)NA * 128 * 4);
  ushort_t* Wh = (ushort_t*)take((size_t)131072 * 2);
  ushort_t* Wlo = (ushort_t*)take((size_t)131072 * 2);
  double* parts = (double*)take((size_t)128 * 512 * 8);
  int* deg = (int*)take((size_t)NA * 4);
  int* cur = (int*)take((size_t)NA * 4);
  int* rp = (int*)take((size_t)(NA + 1) * 4);
  int* col = (int*)take((size_t)NE * 4);
  int* chist = (int*)take((size_t)2 * NCELL * 4);
  int* crp = (int*)take((size_t)(2 * NCELL + 1) * 4);
  int* ccur = (int*)take((size_t)2 * NCELL * 4);
  float2* ps = (float2*)take((size_t)2 * NA * 8);
  int* pid = (int*)take((size_t)2 * NA * 4);

  // setup: zero+packw, hist+self, scans, scatters, nbr, GATs
  k_zero_packw<<<131072 / 256, 256, 0, stream>>>(deg, cur, chist, ccur, gfW, Wh, Wlo);
  k_hist_self<<<(NE + 2 * NA + 8 * NA + 255) / 256, 256, 0, stream>>>(edst, apos, tpos, deg, chist,
                                                                      own_obs, W_self, b_self, x);
  k_scan_all<<<2, 1024, 0, stream>>>(deg, rp, chist, crp);
  k_scatter_all<<<(NE + 2 * NA + 255) / 256, 256, 0, stream>>>(esrc, edst, rp, cur, col,
                                                               apos, tpos, crp, ccur, ps, pid);
  k_nbr2<<<(2 * NA + 255) / 256, 256, 0, stream>>>(apos, crp, ps, pid, a_idx, a_cnt, t_idx, t_cnt);
  k_gat2<<<2 * GATB, 64, 0, stream>>>(apos, tpos, a_idx, a_cnt, t_idx, t_cnt,
                                      agWl, agWr, agatt, agb, tgWl, tgWr, tgatt, tgb, x);

  // two graph-filter + BN + residual layers
  for (int l = 0; l < 2; ++l) {
    const ushort_t* Whl = Wh + (size_t)l * 65536;
    const ushort_t* Wll = Wlo + (size_t)l * 65536;
    const float* bl = gfb + (size_t)l * 128;
    const float* gl = bng + (size_t)l * 128;
    const float* bb = bnb + (size_t)l * 128;
    k_shift3<<<1256, 256, 0, stream>>>(x, sh1, rp, col);
    k_shift3<<<1256, 256, 0, stream>>>(sh1, sh2, rp, col);
    k_shift3<<<1256, 256, 0, stream>>>(sh2, sh3, rp, col);
    k_gemm_mfma3<<<NA / 16, 256, 0, stream>>>(x, sh1, sh2, sh3, Whl, Wll, bl, y);
    k_bnred<<<128, 256, 0, stream>>>(y, parts);
    k_bnapply_f<<<256, 256, 0, stream>>>(y, parts, gl, bb, x);
  }

  k_read<<<(NA + 255) / 256, 256, 0, stream>>>(x, Wread, bread, (float*)d_out);
}